// Round 7
// baseline (7127.602 us; speedup 1.0000x reference)
//
#include <hip/hip_runtime.h>
#include <stdint.h>
#include <math.h>

#define NV 8192
#define EMB 512
#define CLS 257
#define DEG 32
#define TV 8
#define RSTRIDE 260   // padded row stride in floats (1040 B, 16B-aligned)

// ---------------------------------------------------------------------------
// Threefry-2x32, 20 rounds — exactly JAX's _threefry2x32. constexpr so the
// input-independent key chain (seed 42) can be baked in at compile time.
// ---------------------------------------------------------------------------
struct KP { uint32_t a, b; };

__host__ __device__ constexpr KP tfc(uint32_t k0, uint32_t k1,
                                     uint32_t x0, uint32_t x1) {
  const uint32_t ks2 = k0 ^ k1 ^ 0x1BD11BDAu;
  uint32_t v0 = x0 + k0, v1 = x1 + k1;
#define QR(r) { v0 += v1; v1 = (v1 << (r)) | (v1 >> (32 - (r))); v1 ^= v0; }
  QR(13) QR(15) QR(26) QR(6)
  v0 += k1;  v1 += ks2 + 1u;
  QR(17) QR(29) QR(16) QR(24)
  v0 += ks2; v1 += k0 + 2u;
  QR(13) QR(15) QR(26) QR(6)
  v0 += k0;  v1 += k1 + 3u;
  QR(17) QR(29) QR(16) QR(24)
  v0 += k1;  v1 += ks2 + 4u;
  QR(13) QR(15) QR(26) QR(6)
  v0 += ks2; v1 += k0 + 5u;
#undef QR
  return KP{v0, v1};
}

struct Seg { KP e[256]; };
constexpr Seg mkseg(KP s) {
  Seg g{};
  g.e[0] = s;
  for (int i = 1; i < 256; ++i) g.e[i] = tfc(g.e[i - 1].a, g.e[i - 1].b, 0u, 0u);
  return g;
}
#define NXTSEG(prev) mkseg(tfc(prev.e[255].a, prev.e[255].b, 0u, 0u))
constexpr Seg SG0 = mkseg(KP{0u, 42u});
constexpr Seg SG1 = NXTSEG(SG0);   constexpr Seg SG2 = NXTSEG(SG1);
constexpr Seg SG3 = NXTSEG(SG2);   constexpr Seg SG4 = NXTSEG(SG3);
constexpr Seg SG5 = NXTSEG(SG4);   constexpr Seg SG6 = NXTSEG(SG5);
constexpr Seg SG7 = NXTSEG(SG6);   constexpr Seg SG8 = NXTSEG(SG7);
constexpr Seg SG9 = NXTSEG(SG8);   constexpr Seg SG10 = NXTSEG(SG9);
constexpr Seg SG11 = NXTSEG(SG10); constexpr Seg SG12 = NXTSEG(SG11);
constexpr Seg SG13 = NXTSEG(SG12); constexpr Seg SG14 = NXTSEG(SG13);
constexpr Seg SG15 = NXTSEG(SG14); constexpr Seg SG16 = NXTSEG(SG15);
constexpr Seg SG17 = NXTSEG(SG16); constexpr Seg SG18 = NXTSEG(SG17);
constexpr Seg SG19 = NXTSEG(SG18); constexpr Seg SG20 = NXTSEG(SG19);
constexpr Seg SG21 = NXTSEG(SG20); constexpr Seg SG22 = NXTSEG(SG21);
constexpr Seg SG23 = NXTSEG(SG22); constexpr Seg SG24 = NXTSEG(SG23);
constexpr Seg SG25 = NXTSEG(SG24); constexpr Seg SG26 = NXTSEG(SG25);
constexpr Seg SG27 = NXTSEG(SG26); constexpr Seg SG28 = NXTSEG(SG27);
constexpr Seg SG29 = NXTSEG(SG28); constexpr Seg SG30 = NXTSEG(SG29);
constexpr Seg SG31 = NXTSEG(SG30);

struct KT { uint32_t hi[8192]; uint32_t lo[8192]; };
constexpr KT mkkt() {
  KT t{};
  const Seg* sg[32] = {
    &SG0,  &SG1,  &SG2,  &SG3,  &SG4,  &SG5,  &SG6,  &SG7,
    &SG8,  &SG9,  &SG10, &SG11, &SG12, &SG13, &SG14, &SG15,
    &SG16, &SG17, &SG18, &SG19, &SG20, &SG21, &SG22, &SG23,
    &SG24, &SG25, &SG26, &SG27, &SG28, &SG29, &SG30, &SG31 };
  for (int s = 0; s < 32; ++s)
    for (int i = 0; i < 256; ++i) {
      const int v = 1 + s * 256 + i;
      if (v < 8192) { t.hi[v] = sg[s]->e[i].a; t.lo[v] = sg[s]->e[i].b; }
    }
  return t;
}
__device__ const KT KEYS = mkkt();

// ---------------------------------------------------------------------------
// K1: graph_emb = mean(embeddings, axis=0)
// ---------------------------------------------------------------------------
__global__ __launch_bounds__(256) void colmean_part(const float* __restrict__ emb,
                                                    float* __restrict__ part) {
  const int b = blockIdx.x;
  const int t = threadIdx.x;
  for (int j = t; j < EMB; j += 256) {
    float s = 0.f;
    const int r0 = b * 128;
    for (int r = 0; r < 128; ++r) s += emb[(size_t)(r0 + r) * EMB + j];
    part[(size_t)b * EMB + j] = s;
  }
}

__global__ __launch_bounds__(256) void colmean_fin(const float* __restrict__ part,
                                                   float* __restrict__ g) {
  const int t = threadIdx.x;
  for (int j = t; j < EMB; j += 256) {
    float s = 0.f;
    for (int b = 0; b < 64; ++b) s += part[(size_t)b * EMB + j];
    g[j] = s / 8192.0f;
  }
}

// ---------------------------------------------------------------------------
// K2: fused 3-layer MLP, TV=8 (bit-identical per-vertex math) + epilogue:
// pl[] = li + gumbel, er[] = exp(li - rowmax).
// ---------------------------------------------------------------------------
__global__ __launch_bounds__(256) void mlp3h(
    const float* __restrict__ emb, const float* __restrict__ g,
    const float* __restrict__ W1, const float* __restrict__ b1,
    const float* __restrict__ W2, const float* __restrict__ b2,
    const float* __restrict__ W3, const float* __restrict__ b3,
    float* __restrict__ pl, float* __restrict__ er)
{
  __shared__ float xs[TV][68];
  __shared__ float gs[EMB];
  __shared__ float h1s[TV][EMB];
  __shared__ float h2s[TV][400];
  __shared__ float redw[TV][4];
  __shared__ float li256s[TV];
  __shared__ float mrs[TV];

  const int t  = threadIdx.x;
  const int tx = t & 63;
  const int ty = t >> 6;
  const int v0 = blockIdx.x * TV;

  for (int j = t; j < EMB; j += 256) gs[j] = g[j];

  float acc[2][8];
#pragma unroll
  for (int a = 0; a < 2; ++a)
#pragma unroll
    for (int b = 0; b < 8; ++b) acc[a][b] = 0.f;

  for (int kc = 0; kc < 8; ++kc) {
    __syncthreads();
    if (t < 128) {
      const int vv = t >> 4;
      const int kk = (t & 15) << 2;
      const float4 s4 = *reinterpret_cast<const float4*>(
          &emb[(size_t)(v0 + vv) * EMB + kc * 64 + kk]);
      xs[vv][kk] = s4.x; xs[vv][kk + 1] = s4.y;
      xs[vv][kk + 2] = s4.z; xs[vv][kk + 3] = s4.w;
    }
    __syncthreads();
    float cacc[2][8];
#pragma unroll
    for (int a = 0; a < 2; ++a)
#pragma unroll
      for (int b = 0; b < 8; ++b) cacc[a][b] = 0.f;
    for (int kk = 0; kk < 64; ++kk) {
      const int k = kc * 64 + kk;
      float w[8];
#pragma unroll
      for (int jj = 0; jj < 8; ++jj) w[jj] = W1[(size_t)k * EMB + tx + 64 * jj];
      float xv[2];
#pragma unroll
      for (int vv = 0; vv < 2; ++vv) xv[vv] = xs[ty * 2 + vv][kk];
#pragma unroll
      for (int vv = 0; vv < 2; ++vv)
#pragma unroll
        for (int jj = 0; jj < 8; ++jj)
          cacc[vv][jj] = fmaf(xv[vv], w[jj], cacc[vv][jj]);
    }
#pragma unroll
    for (int a = 0; a < 2; ++a)
#pragma unroll
      for (int b = 0; b < 8; ++b) acc[a][b] += cacc[a][b];
  }

  float gacc[8];
#pragma unroll
  for (int b = 0; b < 8; ++b) gacc[b] = 0.f;
  for (int kc = 0; kc < 8; ++kc) {
    float cg[8];
#pragma unroll
    for (int b = 0; b < 8; ++b) cg[b] = 0.f;
    for (int kk = 0; kk < 64; ++kk) {
      const int k = kc * 64 + kk;
      const float gv = gs[k];
#pragma unroll
      for (int jj = 0; jj < 8; ++jj)
        cg[jj] = fmaf(gv, W1[(size_t)(EMB + k) * EMB + tx + 64 * jj], cg[jj]);
    }
#pragma unroll
    for (int b = 0; b < 8; ++b) gacc[b] += cg[b];
  }

#pragma unroll
  for (int jj = 0; jj < 8; ++jj) {
    const int j = tx + 64 * jj;
    const float bj = b1[j];
#pragma unroll
    for (int vv = 0; vv < 2; ++vv) {
      float h = (acc[vv][jj] + gacc[jj]) + bj;
      h = (h >= 0.f) ? h : 0.01f * h;
      h1s[ty * 2 + vv][j] = h;
    }
  }
  __syncthreads();

  const int j2a = t;
  const int j2b = t + 256;
  float a2[TV], a2b[TV];
#pragma unroll
  for (int vv = 0; vv < TV; ++vv) { a2[vv] = 0.f; a2b[vv] = 0.f; }
  for (int kc = 0; kc < 8; ++kc) {
    float c2[TV], c2b[TV];
#pragma unroll
    for (int vv = 0; vv < TV; ++vv) { c2[vv] = 0.f; c2b[vv] = 0.f; }
    for (int kk = 0; kk < 64; ++kk) {
      const int k = kc * 64 + kk;
      const float w0  = W2[(size_t)k * 400 + j2a];
      const float w1v = (j2b < 400) ? W2[(size_t)k * 400 + j2b] : 0.f;
#pragma unroll
      for (int vv = 0; vv < TV; ++vv) {
        const float hv = h1s[vv][k];
        c2[vv]  = fmaf(hv, w0,  c2[vv]);
        c2b[vv] = fmaf(hv, w1v, c2b[vv]);
      }
    }
#pragma unroll
    for (int vv = 0; vv < TV; ++vv) { a2[vv] += c2[vv]; a2b[vv] += c2b[vv]; }
  }
  {
    const float bja = b2[j2a];
#pragma unroll
    for (int vv = 0; vv < TV; ++vv) {
      float h = a2[vv] + bja;
      h2s[vv][j2a] = (h >= 0.f) ? h : 0.01f * h;
    }
    if (j2b < 400) {
      const float bjb = b2[j2b];
#pragma unroll
      for (int vv = 0; vv < TV; ++vv) {
        float h = a2b[vv] + bjb;
        h2s[vv][j2b] = (h >= 0.f) ? h : 0.01f * h;
      }
    }
  }
  __syncthreads();

  float a3[TV], a3x[TV];
#pragma unroll
  for (int vv = 0; vv < TV; ++vv) { a3[vv] = 0.f; a3x[vv] = 0.f; }
  for (int kc = 0; kc < 8; ++kc) {
    float c3[TV], c3x[TV];
#pragma unroll
    for (int vv = 0; vv < TV; ++vv) { c3[vv] = 0.f; c3x[vv] = 0.f; }
    for (int kk = 0; kk < 50; ++kk) {
      const int k = kc * 50 + kk;
      const float w0 = W3[(size_t)k * CLS + t];
      const float wx = (t == 0) ? W3[(size_t)k * CLS + 256] : 0.f;
#pragma unroll
      for (int vv = 0; vv < TV; ++vv) {
        const float hv = h2s[vv][k];
        c3[vv]  = fmaf(hv, w0, c3[vv]);
        c3x[vv] = fmaf(hv, wx, c3x[vv]);
      }
    }
#pragma unroll
    for (int vv = 0; vv < TV; ++vv) { a3[vv] += c3[vv]; a3x[vv] += c3x[vv]; }
  }

  const float bj = b3[t];
  float li_[TV];
#pragma unroll
  for (int vv = 0; vv < TV; ++vv) li_[vv] = a3[vv] + bj;

#pragma unroll
  for (int vv = 0; vv < TV; ++vv) {
    float m = li_[vv];
#pragma unroll
    for (int off = 1; off < 64; off <<= 1) m = fmaxf(m, __shfl_xor(m, off));
    if ((t & 63) == 0) redw[vv][t >> 6] = m;
  }
  if (t == 0) {
    const float bx = b3[256];
#pragma unroll
    for (int vv = 0; vv < TV; ++vv) li256s[vv] = a3x[vv] + bx;
  }
  __syncthreads();
  if (t < TV) {
    const float m = fmaxf(fmaxf(redw[t][0], redw[t][1]),
                          fmaxf(redw[t][2], redw[t][3]));
    mrs[t] = fmaxf(m, li256s[t]);
  }
  __syncthreads();

#pragma unroll
  for (int vv = 0; vv < TV; ++vv) {
    const int v = v0 + vv;
    const float li = li_[vv];
    const KP sk = tfc(KEYS.hi[v], KEYS.lo[v], 0u, 1u);
    const KP o  = tfc(sk.a, sk.b, 0u, (uint32_t)t);
    const uint32_t bb = o.a ^ o.b;
    const float f = __uint_as_float(0x3f800000u | (bb >> 9)) - 1.0f;
    const float u = fmaxf(1.17549435e-38f, f);
    const float gg = -logf(-logf(u));
    pl[(size_t)v * RSTRIDE + t] = li + gg;
    er[(size_t)v * RSTRIDE + t] = expf(li - mrs[vv]);
  }
  if (t == 0) {
    const float bx = b3[256];
#pragma unroll
    for (int vv = 0; vv < TV; ++vv) {
      const int v = v0 + vv;
      const float li = a3x[vv] + bx;
      const KP sk = tfc(KEYS.hi[v], KEYS.lo[v], 0u, 1u);
      const KP o  = tfc(sk.a, sk.b, 0u, 256u);
      const uint32_t bb = o.a ^ o.b;
      const float f = __uint_as_float(0x3f800000u | (bb >> 9)) - 1.0f;
      const float u = fmaxf(1.17549435e-38f, f);
      const float gg = -logf(-logf(u));
      pl[(size_t)v * RSTRIDE + 256] = li + gg;
      er[(size_t)v * RSTRIDE + 256] = expf(li - mrs[vv]);
    }
  }
}

// ---------------------------------------------------------------------------
// helpers
// ---------------------------------------------------------------------------
#define DPPF(CTRL, OLDI, X) \
  __builtin_amdgcn_update_dpp((int)(OLDI), (X), (CTRL), 0xF, 0xF, false)
#define SRED(CTRL) { S += __int_as_float(DPPF(CTRL, 0, __float_as_int(S))); }

__device__ __forceinline__ uint32_t ordmap(float f) {
  const uint32_t s = __float_as_uint(f);
  return s ^ (0x80000000u | (uint32_t)((int32_t)s >> 31));
}

#define WG_SCOPE __HIP_MEMORY_SCOPE_WORKGROUP

// ---------------------------------------------------------------------------
// K2b: per-row descending sort of 257 perturbed logits by (ordmap(pl), ~idx).
// First 320 u16 of each pl row overwritten IN PLACE with sorted class ids.
// ---------------------------------------------------------------------------
__global__ __launch_bounds__(256) void sortrows(float* __restrict__ plbuf) {
  __shared__ uint64_t keys[4][512];
  const int t = threadIdx.x;
  const int w = t >> 6;
  const int lane = t & 63;
  const int v = blockIdx.x * 4 + w;
  const float* row = plbuf + (size_t)v * RSTRIDE;

#pragma unroll
  for (int j = 0; j < 8; ++j) {
    const int i = lane + 64 * j;
    uint32_t om = 0u;
    if (i < CLS) om = ordmap(row[i]);
    keys[w][i] = ((uint64_t)om << 9) | (uint64_t)(511 - i);
  }
  __syncthreads();

  for (int k = 2; k <= 512; k <<= 1) {
    for (int j = k >> 1; j > 0; j >>= 1) {
#pragma unroll
      for (int m = 0; m < 4; ++m) {
        const int p  = lane + 64 * m;
        const int i  = ((p & ~(j - 1)) << 1) | (p & (j - 1));
        const int ix = i | j;
        const uint64_t a = keys[w][i], b = keys[w][ix];
        const bool sw = ((i & k) == 0) ? (a < b) : (a > b);
        if (sw) { keys[w][i] = b; keys[w][ix] = a; }
      }
      __syncthreads();
    }
  }

  uint16_t* o16 = reinterpret_cast<uint16_t*>(plbuf) + (size_t)v * (RSTRIDE * 2);
#pragma unroll
  for (int j = 0; j < 5; ++j) {
    const int i = lane + 64 * j;
    if (i < 320) o16[i] = (uint16_t)(511u - (uint32_t)(keys[w][i] & 511u));
  }
}

// ---------------------------------------------------------------------------
// K3: producer-consumer scan, 3-stage LDS pipeline:
//   step v: P1 critical(v) | P2 or+readback row v+2 | P3 zero+gather row v+3
//           | P4 candload+flags row v+4.
// Mask for row r = gather at step r-3 (colors<=r-3) + 2 register fixes
// (chosen[r-1] via h1, chosen[r-2] via h2). Unrolled x2 with named reg sets.
// ---------------------------------------------------------------------------
#define CRITICAL(V_, CC, CB, H1, H2)                                           \
  {                                                                            \
    const int nu_ = n_used, fx1_ = cp1, fx2_ = cp2;                            \
    bool al_[5];                                                               \
    _Pragma("unroll")                                                          \
    for (int j = 0; j < 5; ++j)                                                \
      al_[j] = (!((CB[j] >> (CC[j] & 31)) & 1u)) &&                            \
               (CC[j] < nu_ || CC[j] == 256) &&                                \
               !(H1 && CC[j] == fx1_) && !(H2 && CC[j] == fx2_);               \
    int raw = 256;                                                             \
    uint64_t b_ = __ballot(al_[0]);                                            \
    if (b_) raw = __builtin_amdgcn_readlane(CC[0], (int)__builtin_ctzll(b_));  \
    else if ((b_ = __ballot(al_[1])))                                          \
      raw = __builtin_amdgcn_readlane(CC[1], (int)__builtin_ctzll(b_));        \
    else if ((b_ = __ballot(al_[2])))                                          \
      raw = __builtin_amdgcn_readlane(CC[2], (int)__builtin_ctzll(b_));        \
    else if ((b_ = __ballot(al_[3])))                                          \
      raw = __builtin_amdgcn_readlane(CC[3], (int)__builtin_ctzll(b_));        \
    else if ((b_ = __ballot(al_[4])))                                          \
      raw = __builtin_amdgcn_readlane(CC[4], (int)__builtin_ctzll(b_));        \
    const bool isnew_ = (raw == 256);                                          \
    const int chosen_ = isnew_ ? nu_ : raw;                                    \
    if (isnew_) ++n_used;                                                      \
    if (lane == 0) {                                                           \
      colors[V_] = chosen_;                                                    \
      rawnu[V_] = (unsigned)raw | ((unsigned)nu_ << 16);                       \
    }                                                                          \
    cp2 = cp1; cp1 = chosen_;                                                  \
  }

#define HALF_STEP(V_, XC, XB, XH1, XH2, XPC, XPH1, XPH2, XPN, XCG, YPN, YCG,   \
                  DO_SYNC)                                                     \
  {                                                                            \
    if (DO_SYNC && (((V_) & 7) == 7)) {                                        \
      if (lane == 0)                                                           \
        __hip_atomic_store(&cons_done, ((V_) + 1) >> 3, __ATOMIC_RELEASE,      \
                           WG_SCOPE);                                          \
      int tgt = (((V_) + 1) >> 3) + 2;                                         \
      if (tgt > 1024) tgt = 1024;                                              \
      while (__hip_atomic_load(&prod_done, __ATOMIC_ACQUIRE, WG_SCOPE) < tgt) {} \
    }                                                                          \
    CRITICAL(V_, XC, XB, XH1, XH2)                                             \
    _Pragma("unroll") for (int j = 0; j < 5; ++j) XC[j] = XPC[j];              \
    XH1 = XPH1; XH2 = XPH2;                                                    \
    /* P2: atomicOr row V_+2 (cg gathered last half-step) + readback */        \
    {                                                                          \
      unsigned* sl_ = bbuf[((V_) + 2) & 3];                                    \
      if (XCG >= 0) atomicOr(&sl_[XCG >> 5], 1u << (XCG & 31));                \
      _Pragma("unroll") for (int j = 0; j < 5; ++j) XB[j] = sl_[XC[j] >> 5];   \
    }                                                                          \
    /* P3: zero slot row V_+3, gather cg for row V_+3 (other set) */           \
    bbuf[((V_) + 3) & 3][lane & 15] = 0u;                                      \
    YCG = colors[YPN];                                                         \
    /* P4: candload row V_+4 + fix-flag ballots */                             \
    {                                                                          \
      const int r4_ = ((V_) + 4 < NV) ? ((V_) + 4) : (NV - 1);                 \
      const int sB_ = (r4_ & 31) * 320;                                        \
      _Pragma("unroll") for (int j = 0; j < 5; ++j)                            \
        XPC[j] = scR16[sB_ + 64 * j + lane];                                   \
      XPN = nbrRing[(((r4_ >> 3) & 3) << 8) + ((r4_ & 7) << 5) + ln32];        \
      XPH1 = (__ballot(XPN == (V_) + 3) != 0ULL);                              \
      XPH2 = (__ballot(XPN == (V_) + 2) != 0ULL);                              \
    }                                                                          \
  }

__global__ __launch_bounds__(128) void scan7(
    const int* __restrict__ nbrG, const uint32_t* __restrict__ scG,
    unsigned* __restrict__ rawnu, float* __restrict__ out)
{
  __shared__ int colors[NV];            // 32 KB
  __shared__ uint32_t scR[32][160];     // 20 KB ring: 320 u16 cands/row
  __shared__ int nbrRing[1024];         // 4 KB: 4 chunks x 8 rows x 32
  __shared__ unsigned bbuf[4][16];      // 4-slot ban-mask ring
  __shared__ int prod_done, cons_done;

  const int t = threadIdx.x;
  const int lane = t & 63;
  const int ln32 = lane & 31;
  const uint16_t* scR16 = reinterpret_cast<const uint16_t*>(&scR[0][0]);

  for (int i = t; i < NV; i += 128) colors[i] = -1;
  if (t == 0) { colors[0] = 0; prod_done = 0; cons_done = 0; }
  __syncthreads();

  if (t >= 64) {
    // ================= producer wave =================
    for (int pc = 0; pc < 1024; ++pc) {
      while (__hip_atomic_load(&cons_done, __ATOMIC_ACQUIRE, WG_SCOPE) < pc - 3)
        __builtin_amdgcn_s_sleep(1);
      uint32_t x[8], y[8], z[8];
#pragma unroll
      for (int r = 0; r < 8; ++r) {
        const size_t base = (size_t)(pc * 8 + r) * RSTRIDE;   // u32 units
        x[r] = scG[base + lane];
        y[r] = scG[base + 64 + lane];
        z[r] = (lane < 32) ? scG[base + 128 + lane] : 0u;
      }
      const int4 nb4 = *reinterpret_cast<const int4*>(nbrG + pc * 256 + 4 * lane);
#pragma unroll
      for (int r = 0; r < 8; ++r) {
        const int slot = (pc * 8 + r) & 31;
        scR[slot][lane] = x[r];
        scR[slot][64 + lane] = y[r];
        if (lane < 32) scR[slot][128 + lane] = z[r];
      }
      *reinterpret_cast<int4*>(&nbrRing[((pc & 3) << 8) + 4 * lane]) = nb4;
      if (lane == 0)
        __hip_atomic_store(&prod_done, pc + 1, __ATOMIC_RELEASE, WG_SCOPE);
    }
    return;
  }

  // ================= consumer wave =================
  while (__hip_atomic_load(&prod_done, __ATOMIC_ACQUIRE, WG_SCOPE) < 2) {}

  int cp1 = 0, cp2 = 0;
  int n_used = 1;

  // ---- slow prologue: rows 1..6, fully serial, complete masks ----
  for (int v = 1; v <= 6; ++v) {
    const int sl = v & 3;
    bbuf[sl][lane & 15] = 0u;
    const int pn = nbrRing[(((v >> 3) & 3) << 8) + ((v & 7) << 5) + ln32];
    const int cg = colors[pn];
    if (cg >= 0) atomicOr(&bbuf[sl][cg >> 5], 1u << (cg & 31));
    int cc[5]; unsigned cb[5];
#pragma unroll
    for (int j = 0; j < 5; ++j) {
      cc[j] = scR16[(v & 31) * 320 + 64 * j + lane];
      cb[j] = bbuf[sl][cc[j] >> 5];
    }
    CRITICAL(v, cc, cb, false, false)
  }

  // ---- prime steady-state pipeline (rows 7..10) ----
  int AC[5], BC[5], APC[5], BPC[5];
  unsigned AB[5], BB[5];
  bool AH1, AH2, BH1, BH2, APH1, APH2, BPH1, BPH2;
  int APN, BPN, ACG, BCG;

  { // row 7: complete mask (colors <= 6 suffice)
    bbuf[3][lane & 15] = 0u;
    const int pn7 = nbrRing[(7 << 5) + ln32];
    const int cg7 = colors[pn7];
    if (cg7 >= 0) atomicOr(&bbuf[3][cg7 >> 5], 1u << (cg7 & 31));
#pragma unroll
    for (int j = 0; j < 5; ++j) {
      AC[j] = scR16[7 * 320 + 64 * j + lane];
      AB[j] = bbuf[3][AC[j] >> 5];
    }
    AH1 = false; AH2 = false;
  }
  { // row 8: mask missing colors[7] only
    bbuf[0][lane & 15] = 0u;
    const int pn8 = nbrRing[(1 << 8) + ln32];
    BH1 = (__ballot(pn8 == 7) != 0ULL); BH2 = false;
    const int cg8 = colors[pn8];
    if (cg8 >= 0) atomicOr(&bbuf[0][cg8 >> 5], 1u << (cg8 & 31));
#pragma unroll
    for (int j = 0; j < 5; ++j) {
      BC[j] = scR16[8 * 320 + 64 * j + lane];
      BB[j] = bbuf[0][BC[j] >> 5];
    }
  }
  { // row 9: zero slot + gather only (or+readback happen at step 7 P2)
    bbuf[1][lane & 15] = 0u;
    const int pn9 = nbrRing[(1 << 8) + (1 << 5) + ln32];
    APH1 = (__ballot(pn9 == 8) != 0ULL);
    APH2 = (__ballot(pn9 == 7) != 0ULL);
    ACG = colors[pn9];
#pragma unroll
    for (int j = 0; j < 5; ++j) APC[j] = scR16[9 * 320 + 64 * j + lane];
  }
  { // row 10: candidates + nbr + flags (gather happens at step 7 P3)
    BPN = nbrRing[(1 << 8) + (2 << 5) + ln32];
    BPH1 = (__ballot(BPN == 9) != 0ULL);
    BPH2 = (__ballot(BPN == 8) != 0ULL);
#pragma unroll
    for (int j = 0; j < 5; ++j) BPC[j] = scR16[10 * 320 + 64 * j + lane];
  }

  // ---- steady-state loop ----
  for (int v = 7; v + 1 < NV; v += 2) {
    HALF_STEP(v,     AC, AB, AH1, AH2, APC, APH1, APH2, APN, ACG, BPN, BCG, true)
    HALF_STEP(v + 1, BC, BB, BH1, BH2, BPC, BPH1, BPH2, BPN, BCG, APN, ACG, false)
  }
  // tail v = 8191 (set A): critical only
  CRITICAL(NV - 1, AC, AB, AH1, AH2)

  for (int i = lane; i < NV; i += 64) out[i] = (float)colors[i];
}

// ---------------------------------------------------------------------------
// K4: parallel logp recomputation (unchanged).
// ---------------------------------------------------------------------------
__global__ __launch_bounds__(256) void logp_part(
    const float* __restrict__ outF, const int* __restrict__ nbrG,
    const float* __restrict__ er, const unsigned* __restrict__ rawnu,
    double* __restrict__ partd)
{
  __shared__ unsigned bb[4][16];
  const int t = threadIdx.x;
  const int w = t >> 6;
  const int lane = t & 63;
  const int ln32 = lane & 31;
  const int b = blockIdx.x;

  double a = 0.0;
  for (int i = 0; i < 32; ++i) {
    const int v = b * 128 + w * 32 + i;
    if (v == 0) continue;
    const unsigned val = rawnu[v];
    const int raw = (int)(val & 0xFFFFu);
    const int nu  = (int)(val >> 16);

    bb[w][lane & 15] = 0u;
    const int u = nbrG[(size_t)v * DEG + ln32];
    const int cu = (u < v) ? (int)outF[u] : -1;
    if (cu >= 0) atomicOr(&bb[w][cu >> 5], 1u << (cu & 31));
    unsigned bwp[4];
#pragma unroll
    for (int j = 0; j < 4; ++j) bwp[j] = bb[w][(lane >> 5) + 2 * j];
    const unsigned bw8 = bb[w][8];

    const size_t base = (size_t)v * RSTRIDE;
    bool mk[4];
    float e[4];
#pragma unroll
    for (int j = 0; j < 4; ++j) {
      const int c = lane + 64 * j;
      mk[j] = (((bwp[j] >> ln32) & 1u) != 0u) || (c >= nu);
      e[j] = mk[j] ? 0.f : er[base + c];
    }
    const bool mkX = ((bw8 & 1u) != 0u);
    const float eX = er[base + 256];
    const float e4 = (!mkX && lane == 0) ? eX : 0.f;

    float S = ((e[0] + e[1]) + (e[2] + e[3])) + e4;
    SRED(0x111) SRED(0x112) SRED(0x114) SRED(0x118) SRED(0x142) SRED(0x143)
    const float Sall = __int_as_float(
        __builtin_amdgcn_readlane(__float_as_int(S), 63));

    const bool isnew = (raw == 256);
    const int jsel  = isnew ? 4 : (raw >> 6);
    const int owner = isnew ? 0 : (raw & 63);
    const float cand = (jsel == 0) ? e[0] : (jsel == 1) ? e[1]
                     : (jsel == 2) ? e[2] : (jsel == 3) ? e[3] : e4;
    const float praw = __int_as_float(
        __builtin_amdgcn_readlane(__float_as_int(cand), owner));

    const float p = praw / Sall;
    a += (double)(logf(p + 1e-8f) - logf(1e-8f));
  }
  if (lane == 0) partd[b * 4 + w] = a;
}

__global__ __launch_bounds__(64) void finalize(
    const double* __restrict__ partd, const unsigned* __restrict__ rawnu,
    const float* __restrict__ baseline, float* __restrict__ out)
{
  if (threadIdx.x == 0) {
    double lp = 0.0;
    for (int i = 0; i < 256; ++i) lp += partd[i];
    const unsigned val = rawnu[NV - 1];
    const unsigned nf = (val >> 16) + (((val & 0xFFFFu) == 256u) ? 1u : 0u);
    out[NV] = ((float)nf - baseline[0]) * (float)lp / 8192.0f;
  }
}

// ---------------------------------------------------------------------------
extern "C" void kernel_launch(void* const* d_in, const int* in_sizes, int n_in,
                              void* d_out, int out_size, void* d_ws, size_t ws_size,
                              hipStream_t stream) {
  const float* emb      = (const float*)d_in[0];
  const int*   nbr      = (const int*)d_in[1];
  const float* W1       = (const float*)d_in[2];
  const float* b1       = (const float*)d_in[3];
  const float* W2       = (const float*)d_in[4];
  const float* b2       = (const float*)d_in[5];
  const float* W3       = (const float*)d_in[6];
  const float* b3       = (const float*)d_in[7];
  const float* baseline = (const float*)d_in[8];
  float* out = (float*)d_out;

  char* ws = (char*)d_ws;
  float* g     = (float*)ws;                               // 2 KB
  float* plbuf = (float*)(ws + 2048);                      // 8192*260*4 B
  float* erbuf = (float*)(ws + 2048 + NV * RSTRIDE * 4);   // 8192*260*4 B
  float* part  = erbuf;  // alias: consumed by colmean_fin BEFORE mlp3h writes er
  unsigned* rawnu = (unsigned*)(ws + 2048);                // aliases dead pl rows
  double*   partd = (double*)(ws + 2048 + 65536);          // 2 KB

  colmean_part<<<64, 256, 0, stream>>>(emb, part);
  colmean_fin<<<1, 256, 0, stream>>>(part, g);
  mlp3h<<<NV / TV, 256, 0, stream>>>(emb, g, W1, b1, W2, b2, W3, b3, plbuf, erbuf);
  sortrows<<<NV / 4, 256, 0, stream>>>(plbuf);
  scan7<<<1, 128, 0, stream>>>(nbr, (const uint32_t*)plbuf, rawnu, out);
  logp_part<<<64, 256, 0, stream>>>((const float*)out, nbr, erbuf, rawnu, partd);
  finalize<<<1, 64, 0, stream>>>(partd, rawnu, baseline, out);
}

// Round 8
// 3967.799 us; speedup vs baseline: 1.7964x; 1.7964x over previous
//
#include <hip/hip_runtime.h>
#include <stdint.h>
#include <math.h>

#define NV 8192
#define EMB 512
#define CLS 257
#define DEG 32
#define TV 8
#define RSTRIDE 260   // padded row stride in floats (1040 B, 16B-aligned)

// ---------------------------------------------------------------------------
// Threefry-2x32, 20 rounds — exactly JAX's _threefry2x32. constexpr so the
// input-independent key chain (seed 42) can be baked in at compile time.
// ---------------------------------------------------------------------------
struct KP { uint32_t a, b; };

__host__ __device__ constexpr KP tfc(uint32_t k0, uint32_t k1,
                                     uint32_t x0, uint32_t x1) {
  const uint32_t ks2 = k0 ^ k1 ^ 0x1BD11BDAu;
  uint32_t v0 = x0 + k0, v1 = x1 + k1;
#define QR(r) { v0 += v1; v1 = (v1 << (r)) | (v1 >> (32 - (r))); v1 ^= v0; }
  QR(13) QR(15) QR(26) QR(6)
  v0 += k1;  v1 += ks2 + 1u;
  QR(17) QR(29) QR(16) QR(24)
  v0 += ks2; v1 += k0 + 2u;
  QR(13) QR(15) QR(26) QR(6)
  v0 += k0;  v1 += k1 + 3u;
  QR(17) QR(29) QR(16) QR(24)
  v0 += k1;  v1 += ks2 + 4u;
  QR(13) QR(15) QR(26) QR(6)
  v0 += ks2; v1 += k0 + 5u;
#undef QR
  return KP{v0, v1};
}

struct Seg { KP e[256]; };
constexpr Seg mkseg(KP s) {
  Seg g{};
  g.e[0] = s;
  for (int i = 1; i < 256; ++i) g.e[i] = tfc(g.e[i - 1].a, g.e[i - 1].b, 0u, 0u);
  return g;
}
#define NXTSEG(prev) mkseg(tfc(prev.e[255].a, prev.e[255].b, 0u, 0u))
constexpr Seg SG0 = mkseg(KP{0u, 42u});
constexpr Seg SG1 = NXTSEG(SG0);   constexpr Seg SG2 = NXTSEG(SG1);
constexpr Seg SG3 = NXTSEG(SG2);   constexpr Seg SG4 = NXTSEG(SG3);
constexpr Seg SG5 = NXTSEG(SG4);   constexpr Seg SG6 = NXTSEG(SG5);
constexpr Seg SG7 = NXTSEG(SG6);   constexpr Seg SG8 = NXTSEG(SG7);
constexpr Seg SG9 = NXTSEG(SG8);   constexpr Seg SG10 = NXTSEG(SG9);
constexpr Seg SG11 = NXTSEG(SG10); constexpr Seg SG12 = NXTSEG(SG11);
constexpr Seg SG13 = NXTSEG(SG12); constexpr Seg SG14 = NXTSEG(SG13);
constexpr Seg SG15 = NXTSEG(SG14); constexpr Seg SG16 = NXTSEG(SG15);
constexpr Seg SG17 = NXTSEG(SG16); constexpr Seg SG18 = NXTSEG(SG17);
constexpr Seg SG19 = NXTSEG(SG18); constexpr Seg SG20 = NXTSEG(SG19);
constexpr Seg SG21 = NXTSEG(SG20); constexpr Seg SG22 = NXTSEG(SG21);
constexpr Seg SG23 = NXTSEG(SG22); constexpr Seg SG24 = NXTSEG(SG23);
constexpr Seg SG25 = NXTSEG(SG24); constexpr Seg SG26 = NXTSEG(SG25);
constexpr Seg SG27 = NXTSEG(SG26); constexpr Seg SG28 = NXTSEG(SG27);
constexpr Seg SG29 = NXTSEG(SG28); constexpr Seg SG30 = NXTSEG(SG29);
constexpr Seg SG31 = NXTSEG(SG30);

struct KT { uint32_t hi[8192]; uint32_t lo[8192]; };
constexpr KT mkkt() {
  KT t{};
  const Seg* sg[32] = {
    &SG0,  &SG1,  &SG2,  &SG3,  &SG4,  &SG5,  &SG6,  &SG7,
    &SG8,  &SG9,  &SG10, &SG11, &SG12, &SG13, &SG14, &SG15,
    &SG16, &SG17, &SG18, &SG19, &SG20, &SG21, &SG22, &SG23,
    &SG24, &SG25, &SG26, &SG27, &SG28, &SG29, &SG30, &SG31 };
  for (int s = 0; s < 32; ++s)
    for (int i = 0; i < 256; ++i) {
      const int v = 1 + s * 256 + i;
      if (v < 8192) { t.hi[v] = sg[s]->e[i].a; t.lo[v] = sg[s]->e[i].b; }
    }
  return t;
}
__device__ const KT KEYS = mkkt();

// ---------------------------------------------------------------------------
// K1: graph_emb = mean(embeddings, axis=0)
// ---------------------------------------------------------------------------
__global__ __launch_bounds__(256) void colmean_part(const float* __restrict__ emb,
                                                    float* __restrict__ part) {
  const int b = blockIdx.x;
  const int t = threadIdx.x;
  for (int j = t; j < EMB; j += 256) {
    float s = 0.f;
    const int r0 = b * 128;
    for (int r = 0; r < 128; ++r) s += emb[(size_t)(r0 + r) * EMB + j];
    part[(size_t)b * EMB + j] = s;
  }
}

__global__ __launch_bounds__(256) void colmean_fin(const float* __restrict__ part,
                                                   float* __restrict__ g) {
  const int t = threadIdx.x;
  for (int j = t; j < EMB; j += 256) {
    float s = 0.f;
    for (int b = 0; b < 64; ++b) s += part[(size_t)b * EMB + j];
    g[j] = s / 8192.0f;
  }
}

// ---------------------------------------------------------------------------
// K2: fused 3-layer MLP, TV=8 (bit-identical per-vertex math) + epilogue:
// pl[] = li + gumbel, er[] = exp(li - rowmax).
// ---------------------------------------------------------------------------
__global__ __launch_bounds__(256) void mlp3h(
    const float* __restrict__ emb, const float* __restrict__ g,
    const float* __restrict__ W1, const float* __restrict__ b1,
    const float* __restrict__ W2, const float* __restrict__ b2,
    const float* __restrict__ W3, const float* __restrict__ b3,
    float* __restrict__ pl, float* __restrict__ er)
{
  __shared__ float xs[TV][68];
  __shared__ float gs[EMB];
  __shared__ float h1s[TV][EMB];
  __shared__ float h2s[TV][400];
  __shared__ float redw[TV][4];
  __shared__ float li256s[TV];
  __shared__ float mrs[TV];

  const int t  = threadIdx.x;
  const int tx = t & 63;
  const int ty = t >> 6;
  const int v0 = blockIdx.x * TV;

  for (int j = t; j < EMB; j += 256) gs[j] = g[j];

  float acc[2][8];
#pragma unroll
  for (int a = 0; a < 2; ++a)
#pragma unroll
    for (int b = 0; b < 8; ++b) acc[a][b] = 0.f;

  for (int kc = 0; kc < 8; ++kc) {
    __syncthreads();
    if (t < 128) {
      const int vv = t >> 4;
      const int kk = (t & 15) << 2;
      const float4 s4 = *reinterpret_cast<const float4*>(
          &emb[(size_t)(v0 + vv) * EMB + kc * 64 + kk]);
      xs[vv][kk] = s4.x; xs[vv][kk + 1] = s4.y;
      xs[vv][kk + 2] = s4.z; xs[vv][kk + 3] = s4.w;
    }
    __syncthreads();
    float cacc[2][8];
#pragma unroll
    for (int a = 0; a < 2; ++a)
#pragma unroll
      for (int b = 0; b < 8; ++b) cacc[a][b] = 0.f;
    for (int kk = 0; kk < 64; ++kk) {
      const int k = kc * 64 + kk;
      float w[8];
#pragma unroll
      for (int jj = 0; jj < 8; ++jj) w[jj] = W1[(size_t)k * EMB + tx + 64 * jj];
      float xv[2];
#pragma unroll
      for (int vv = 0; vv < 2; ++vv) xv[vv] = xs[ty * 2 + vv][kk];
#pragma unroll
      for (int vv = 0; vv < 2; ++vv)
#pragma unroll
        for (int jj = 0; jj < 8; ++jj)
          cacc[vv][jj] = fmaf(xv[vv], w[jj], cacc[vv][jj]);
    }
#pragma unroll
    for (int a = 0; a < 2; ++a)
#pragma unroll
      for (int b = 0; b < 8; ++b) acc[a][b] += cacc[a][b];
  }

  float gacc[8];
#pragma unroll
  for (int b = 0; b < 8; ++b) gacc[b] = 0.f;
  for (int kc = 0; kc < 8; ++kc) {
    float cg[8];
#pragma unroll
    for (int b = 0; b < 8; ++b) cg[b] = 0.f;
    for (int kk = 0; kk < 64; ++kk) {
      const int k = kc * 64 + kk;
      const float gv = gs[k];
#pragma unroll
      for (int jj = 0; jj < 8; ++jj)
        cg[jj] = fmaf(gv, W1[(size_t)(EMB + k) * EMB + tx + 64 * jj], cg[jj]);
    }
#pragma unroll
    for (int b = 0; b < 8; ++b) gacc[b] += cg[b];
  }

#pragma unroll
  for (int jj = 0; jj < 8; ++jj) {
    const int j = tx + 64 * jj;
    const float bj = b1[j];
#pragma unroll
    for (int vv = 0; vv < 2; ++vv) {
      float h = (acc[vv][jj] + gacc[jj]) + bj;
      h = (h >= 0.f) ? h : 0.01f * h;
      h1s[ty * 2 + vv][j] = h;
    }
  }
  __syncthreads();

  const int j2a = t;
  const int j2b = t + 256;
  float a2[TV], a2b[TV];
#pragma unroll
  for (int vv = 0; vv < TV; ++vv) { a2[vv] = 0.f; a2b[vv] = 0.f; }
  for (int kc = 0; kc < 8; ++kc) {
    float c2[TV], c2b[TV];
#pragma unroll
    for (int vv = 0; vv < TV; ++vv) { c2[vv] = 0.f; c2b[vv] = 0.f; }
    for (int kk = 0; kk < 64; ++kk) {
      const int k = kc * 64 + kk;
      const float w0  = W2[(size_t)k * 400 + j2a];
      const float w1v = (j2b < 400) ? W2[(size_t)k * 400 + j2b] : 0.f;
#pragma unroll
      for (int vv = 0; vv < TV; ++vv) {
        const float hv = h1s[vv][k];
        c2[vv]  = fmaf(hv, w0,  c2[vv]);
        c2b[vv] = fmaf(hv, w1v, c2b[vv]);
      }
    }
#pragma unroll
    for (int vv = 0; vv < TV; ++vv) { a2[vv] += c2[vv]; a2b[vv] += c2b[vv]; }
  }
  {
    const float bja = b2[j2a];
#pragma unroll
    for (int vv = 0; vv < TV; ++vv) {
      float h = a2[vv] + bja;
      h2s[vv][j2a] = (h >= 0.f) ? h : 0.01f * h;
    }
    if (j2b < 400) {
      const float bjb = b2[j2b];
#pragma unroll
      for (int vv = 0; vv < TV; ++vv) {
        float h = a2b[vv] + bjb;
        h2s[vv][j2b] = (h >= 0.f) ? h : 0.01f * h;
      }
    }
  }
  __syncthreads();

  float a3[TV], a3x[TV];
#pragma unroll
  for (int vv = 0; vv < TV; ++vv) { a3[vv] = 0.f; a3x[vv] = 0.f; }
  for (int kc = 0; kc < 8; ++kc) {
    float c3[TV], c3x[TV];
#pragma unroll
    for (int vv = 0; vv < TV; ++vv) { c3[vv] = 0.f; c3x[vv] = 0.f; }
    for (int kk = 0; kk < 50; ++kk) {
      const int k = kc * 50 + kk;
      const float w0 = W3[(size_t)k * CLS + t];
      const float wx = (t == 0) ? W3[(size_t)k * CLS + 256] : 0.f;
#pragma unroll
      for (int vv = 0; vv < TV; ++vv) {
        const float hv = h2s[vv][k];
        c3[vv]  = fmaf(hv, w0, c3[vv]);
        c3x[vv] = fmaf(hv, wx, c3x[vv]);
      }
    }
#pragma unroll
    for (int vv = 0; vv < TV; ++vv) { a3[vv] += c3[vv]; a3x[vv] += c3x[vv]; }
  }

  const float bj = b3[t];
  float li_[TV];
#pragma unroll
  for (int vv = 0; vv < TV; ++vv) li_[vv] = a3[vv] + bj;

#pragma unroll
  for (int vv = 0; vv < TV; ++vv) {
    float m = li_[vv];
#pragma unroll
    for (int off = 1; off < 64; off <<= 1) m = fmaxf(m, __shfl_xor(m, off));
    if ((t & 63) == 0) redw[vv][t >> 6] = m;
  }
  if (t == 0) {
    const float bx = b3[256];
#pragma unroll
    for (int vv = 0; vv < TV; ++vv) li256s[vv] = a3x[vv] + bx;
  }
  __syncthreads();
  if (t < TV) {
    const float m = fmaxf(fmaxf(redw[t][0], redw[t][1]),
                          fmaxf(redw[t][2], redw[t][3]));
    mrs[t] = fmaxf(m, li256s[t]);
  }
  __syncthreads();

#pragma unroll
  for (int vv = 0; vv < TV; ++vv) {
    const int v = v0 + vv;
    const float li = li_[vv];
    const KP sk = tfc(KEYS.hi[v], KEYS.lo[v], 0u, 1u);
    const KP o  = tfc(sk.a, sk.b, 0u, (uint32_t)t);
    const uint32_t bb = o.a ^ o.b;
    const float f = __uint_as_float(0x3f800000u | (bb >> 9)) - 1.0f;
    const float u = fmaxf(1.17549435e-38f, f);
    const float gg = -logf(-logf(u));
    pl[(size_t)v * RSTRIDE + t] = li + gg;
    er[(size_t)v * RSTRIDE + t] = expf(li - mrs[vv]);
  }
  if (t == 0) {
    const float bx = b3[256];
#pragma unroll
    for (int vv = 0; vv < TV; ++vv) {
      const int v = v0 + vv;
      const float li = a3x[vv] + bx;
      const KP sk = tfc(KEYS.hi[v], KEYS.lo[v], 0u, 1u);
      const KP o  = tfc(sk.a, sk.b, 0u, 256u);
      const uint32_t bb = o.a ^ o.b;
      const float f = __uint_as_float(0x3f800000u | (bb >> 9)) - 1.0f;
      const float u = fmaxf(1.17549435e-38f, f);
      const float gg = -logf(-logf(u));
      pl[(size_t)v * RSTRIDE + 256] = li + gg;
      er[(size_t)v * RSTRIDE + 256] = expf(li - mrs[vv]);
    }
  }
}

// ---------------------------------------------------------------------------
// helpers
// ---------------------------------------------------------------------------
#define DPPF(CTRL, OLDI, X) \
  __builtin_amdgcn_update_dpp((int)(OLDI), (X), (CTRL), 0xF, 0xF, false)
#define SRED(CTRL) { S += __int_as_float(DPPF(CTRL, 0, __float_as_int(S))); }

__device__ __forceinline__ uint32_t ordmap(float f) {
  const uint32_t s = __float_as_uint(f);
  return s ^ (0x80000000u | (uint32_t)((int32_t)s >> 31));
}

#define WG_SCOPE __HIP_MEMORY_SCOPE_WORKGROUP

// ---------------------------------------------------------------------------
// K2b: per-row descending sort of 257 perturbed logits by (ordmap(pl), ~idx).
// First 320 u16 of each pl row overwritten IN PLACE with sorted class ids.
// ---------------------------------------------------------------------------
__global__ __launch_bounds__(256) void sortrows(float* __restrict__ plbuf) {
  __shared__ uint64_t keys[4][512];
  const int t = threadIdx.x;
  const int w = t >> 6;
  const int lane = t & 63;
  const int v = blockIdx.x * 4 + w;
  const float* row = plbuf + (size_t)v * RSTRIDE;

#pragma unroll
  for (int j = 0; j < 8; ++j) {
    const int i = lane + 64 * j;
    uint32_t om = 0u;
    if (i < CLS) om = ordmap(row[i]);
    keys[w][i] = ((uint64_t)om << 9) | (uint64_t)(511 - i);
  }
  __syncthreads();

  for (int k = 2; k <= 512; k <<= 1) {
    for (int j = k >> 1; j > 0; j >>= 1) {
#pragma unroll
      for (int m = 0; m < 4; ++m) {
        const int p  = lane + 64 * m;
        const int i  = ((p & ~(j - 1)) << 1) | (p & (j - 1));
        const int ix = i | j;
        const uint64_t a = keys[w][i], b = keys[w][ix];
        const bool sw = ((i & k) == 0) ? (a < b) : (a > b);
        if (sw) { keys[w][i] = b; keys[w][ix] = a; }
      }
      __syncthreads();
    }
  }

  uint16_t* o16 = reinterpret_cast<uint16_t*>(plbuf) + (size_t)v * (RSTRIDE * 2);
#pragma unroll
  for (int j = 0; j < 5; ++j) {
    const int i = lane + 64 * j;
    if (i < 320) o16[i] = (uint16_t)(511u - (uint32_t)(keys[w][i] & 511u));
  }
}

// ---------------------------------------------------------------------------
// K3: producer-consumer scan (scan5 structure) with top-128 fast path.
// Per iter: prefetch chunks 0-1 of row v+1 + precomputed allowed-bits (both
// nu and nu+1 variants); critical = 1-2 ballots; uniform-branch slow path
// reads chunks 2-4 + ban slot v&1 from the ring on miss (rare).
// ---------------------------------------------------------------------------
__global__ __launch_bounds__(128) void scan8(
    const int* __restrict__ nbrG, const uint32_t* __restrict__ scG,
    unsigned* __restrict__ rawnu, float* __restrict__ out)
{
  __shared__ int colors[NV];            // 32 KB
  __shared__ uint32_t scR[32][160];     // 20 KB ring: 320 u16 cands/row
  __shared__ int nbrRing[1024];         // 4 KB: 4 chunks x 8 rows x 32
  __shared__ unsigned bbuf[2][16];
  __shared__ int prod_done, cons_done;

  const int t = threadIdx.x;
  const int lane = t & 63;
  const int ln32 = lane & 31;
  const uint16_t* scR16 = reinterpret_cast<const uint16_t*>(&scR[0][0]);

  for (int i = t; i < NV; i += 128) colors[i] = -1;
  if (t == 0) { colors[0] = 0; prod_done = 0; cons_done = 0; }
  __syncthreads();

  if (t >= 64) {
    // ================= producer wave =================
    for (int pc = 0; pc < 1024; ++pc) {
      while (__hip_atomic_load(&cons_done, __ATOMIC_ACQUIRE, WG_SCOPE) < pc - 3)
        __builtin_amdgcn_s_sleep(1);
      uint32_t x[8], y[8], z[8];
#pragma unroll
      for (int r = 0; r < 8; ++r) {
        const size_t base = (size_t)(pc * 8 + r) * RSTRIDE;   // u32 units
        x[r] = scG[base + lane];
        y[r] = scG[base + 64 + lane];
        z[r] = (lane < 32) ? scG[base + 128 + lane] : 0u;
      }
      const int4 nb4 = *reinterpret_cast<const int4*>(nbrG + pc * 256 + 4 * lane);
#pragma unroll
      for (int r = 0; r < 8; ++r) {
        const int slot = (pc * 8 + r) & 31;
        scR[slot][lane] = x[r];
        scR[slot][64 + lane] = y[r];
        if (lane < 32) scR[slot][128 + lane] = z[r];
      }
      *reinterpret_cast<int4*>(&nbrRing[((pc & 3) << 8) + 4 * lane]) = nb4;
      if (lane == 0)
        __hip_atomic_store(&prod_done, pc + 1, __ATOMIC_RELEASE, WG_SCOPE);
    }
    return;
  }

  // ================= consumer wave =================
  while (__hip_atomic_load(&prod_done, __ATOMIC_ACQUIRE, WG_SCOPE) < 2) {}

  // prologue: state for v = 1
  int c0, c1;
  bool s0a, s0b, s1a, s1b, hf;
  int nbrn;
  {
    const int nb1 = nbrRing[32 + ln32];           // row 1, chunk 0
    bbuf[1][lane & 15] = 0u;
    hf = (__ballot(nb1 == 0) != 0ULL);
    const int cg0 = colors[nb1];
    if (cg0 >= 0) atomicOr(&bbuf[1][cg0 >> 5], 1u << (cg0 & 31));
    c0 = scR16[320 + lane];
    c1 = scR16[320 + 64 + lane];
    const unsigned w0 = bbuf[1][c0 >> 5];
    const unsigned w1 = bbuf[1][c1 >> 5];
    const bool f0 = !((w0 >> (c0 & 31)) & 1u);
    const bool f1 = !((w1 >> (c1 & 31)) & 1u);
    s0a = f0 && (c0 < 1 || c0 == 256);
    s0b = f0 && (c0 < 2 || c0 == 256);
    s1a = f1 && (c1 < 1 || c1 == 256);
    s1b = f1 && (c1 < 2 || c1 == 256);
    nbrn = nbrRing[64 + ln32];                    // row 2, chunk 0
  }

  int chosen_prev = 0;
  int n_used = 1;
  bool inP = false;   // did step v-1 allocate a new color?

  for (int v = 1; v < NV; ++v) {
    const int vp1 = (v + 1 < NV) ? v + 1 : NV - 1;
    const int vp2 = (v + 2 < NV) ? v + 2 : NV - 1;

    // ---- chunk sync (1/8 iters) ----
    if ((v & 7) == 7) {
      if (lane == 0)
        __hip_atomic_store(&cons_done, (v + 1) >> 3, __ATOMIC_RELEASE, WG_SCOPE);
      int tgt = ((v + 1) >> 3) + 2;
      tgt = tgt > 1024 ? 1024 : tgt;
      while (__hip_atomic_load(&prod_done, __ATOMIC_ACQUIRE, WG_SCOPE) < tgt) {}
    }

    // ---- prefetch phase: chunks 0-1 + mask for v+1 (both nu variants) ----
    const int sB = (vp1 & 31) * 320;
    const int n0 = scR16[sB + lane];
    const int n1 = scR16[sB + 64 + lane];
    const int nbrn2 = nbrRing[(((vp2 >> 3) & 3) << 8) + ((vp2 & 7) << 5) + ln32];

    const int nb = vp1 & 1;
    bbuf[nb][lane & 15] = 0u;
    const bool hfn = (__ballot(nbrn == v) != 0ULL);
    const int cgn = colors[nbrn];                 // stale gather (misses only v)
    if (cgn >= 0) atomicOr(&bbuf[nb][cgn >> 5], 1u << (cgn & 31));
    const unsigned wn0 = bbuf[nb][n0 >> 5];
    const unsigned wn1 = bbuf[nb][n1 >> 5];
    const int nuP = n_used;
    const bool fn0 = !((wn0 >> (n0 & 31)) & 1u);
    const bool fn1 = !((wn1 >> (n1 & 31)) & 1u);
    const bool sn0a = fn0 && (n0 < nuP || n0 == 256);
    const bool sn0b = fn0 && (n0 < nuP + 1 || n0 == 256);
    const bool sn1a = fn1 && (n1 < nuP || n1 == 256);
    const bool sn1b = fn1 && (n1 < nuP + 1 || n1 == 256);

    // ---- critical phase for v ----
    const int fixc = chosen_prev;
    int raw = 256;
    {
      const bool ok0 = (inP ? s0b : s0a) && !(hf && c0 == fixc);
      uint64_t b_ = __ballot(ok0);
      if (b_) {
        raw = __builtin_amdgcn_readlane(c0, (int)__builtin_ctzll(b_));
      } else {
        const bool ok1 = (inP ? s1b : s1a) && !(hf && c1 == fixc);
        b_ = __ballot(ok1);
        if (b_) {
          raw = __builtin_amdgcn_readlane(c1, (int)__builtin_ctzll(b_));
        } else {
          // slow path: chunks 2-4 of row v + ban slot v&1 (intact this iter)
          const int sBv = (v & 31) * 320;
          const int nu = n_used;
          const int x2 = scR16[sBv + 128 + lane];
          const int x3 = scR16[sBv + 192 + lane];
          const int x4 = scR16[sBv + 256 + lane];
          const unsigned q2 = bbuf[v & 1][x2 >> 5];
          const unsigned q3 = bbuf[v & 1][x3 >> 5];
          const unsigned q4 = bbuf[v & 1][x4 >> 5];
          const bool o2 = (!((q2 >> (x2 & 31)) & 1u)) &&
                          (x2 < nu || x2 == 256) && !(hf && x2 == fixc);
          const bool o3 = (!((q3 >> (x3 & 31)) & 1u)) &&
                          (x3 < nu || x3 == 256) && !(hf && x3 == fixc);
          const bool o4 = (!((q4 >> (x4 & 31)) & 1u)) &&
                          (x4 < nu || x4 == 256) && !(hf && x4 == fixc);
          if ((b_ = __ballot(o2)))
            raw = __builtin_amdgcn_readlane(x2, (int)__builtin_ctzll(b_));
          else if ((b_ = __ballot(o3)))
            raw = __builtin_amdgcn_readlane(x3, (int)__builtin_ctzll(b_));
          else if ((b_ = __ballot(o4)))
            raw = __builtin_amdgcn_readlane(x4, (int)__builtin_ctzll(b_));
        }
      }
    }

    const bool isnew = (raw == 256);
    const int chosen = isnew ? n_used : raw;
    if (lane == 0) {
      colors[v] = chosen;
      rawnu[v] = (unsigned)raw | ((unsigned)n_used << 16);
    }
    if (isnew) ++n_used;
    inP = isnew;
    chosen_prev = chosen;

    // ---- shift pipelined state ----
    c0 = n0; c1 = n1;
    s0a = sn0a; s0b = sn0b; s1a = sn1a; s1b = sn1b;
    hf = hfn; nbrn = nbrn2;
  }

  for (int i = lane; i < NV; i += 64) out[i] = (float)colors[i];
}

// ---------------------------------------------------------------------------
// K4: parallel logp recomputation (unchanged).
// ---------------------------------------------------------------------------
__global__ __launch_bounds__(256) void logp_part(
    const float* __restrict__ outF, const int* __restrict__ nbrG,
    const float* __restrict__ er, const unsigned* __restrict__ rawnu,
    double* __restrict__ partd)
{
  __shared__ unsigned bb[4][16];
  const int t = threadIdx.x;
  const int w = t >> 6;
  const int lane = t & 63;
  const int ln32 = lane & 31;
  const int b = blockIdx.x;

  double a = 0.0;
  for (int i = 0; i < 32; ++i) {
    const int v = b * 128 + w * 32 + i;
    if (v == 0) continue;
    const unsigned val = rawnu[v];
    const int raw = (int)(val & 0xFFFFu);
    const int nu  = (int)(val >> 16);

    bb[w][lane & 15] = 0u;
    const int u = nbrG[(size_t)v * DEG + ln32];
    const int cu = (u < v) ? (int)outF[u] : -1;
    if (cu >= 0) atomicOr(&bb[w][cu >> 5], 1u << (cu & 31));
    unsigned bwp[4];
#pragma unroll
    for (int j = 0; j < 4; ++j) bwp[j] = bb[w][(lane >> 5) + 2 * j];
    const unsigned bw8 = bb[w][8];

    const size_t base = (size_t)v * RSTRIDE;
    bool mk[4];
    float e[4];
#pragma unroll
    for (int j = 0; j < 4; ++j) {
      const int c = lane + 64 * j;
      mk[j] = (((bwp[j] >> ln32) & 1u) != 0u) || (c >= nu);
      e[j] = mk[j] ? 0.f : er[base + c];
    }
    const bool mkX = ((bw8 & 1u) != 0u);
    const float eX = er[base + 256];
    const float e4 = (!mkX && lane == 0) ? eX : 0.f;

    float S = ((e[0] + e[1]) + (e[2] + e[3])) + e4;
    SRED(0x111) SRED(0x112) SRED(0x114) SRED(0x118) SRED(0x142) SRED(0x143)
    const float Sall = __int_as_float(
        __builtin_amdgcn_readlane(__float_as_int(S), 63));

    const bool isnew = (raw == 256);
    const int jsel  = isnew ? 4 : (raw >> 6);
    const int owner = isnew ? 0 : (raw & 63);
    const float cand = (jsel == 0) ? e[0] : (jsel == 1) ? e[1]
                     : (jsel == 2) ? e[2] : (jsel == 3) ? e[3] : e4;
    const float praw = __int_as_float(
        __builtin_amdgcn_readlane(__float_as_int(cand), owner));

    const float p = praw / Sall;
    a += (double)(logf(p + 1e-8f) - logf(1e-8f));
  }
  if (lane == 0) partd[b * 4 + w] = a;
}

__global__ __launch_bounds__(64) void finalize(
    const double* __restrict__ partd, const unsigned* __restrict__ rawnu,
    const float* __restrict__ baseline, float* __restrict__ out)
{
  if (threadIdx.x == 0) {
    double lp = 0.0;
    for (int i = 0; i < 256; ++i) lp += partd[i];
    const unsigned val = rawnu[NV - 1];
    const unsigned nf = (val >> 16) + (((val & 0xFFFFu) == 256u) ? 1u : 0u);
    out[NV] = ((float)nf - baseline[0]) * (float)lp / 8192.0f;
  }
}

// ---------------------------------------------------------------------------
extern "C" void kernel_launch(void* const* d_in, const int* in_sizes, int n_in,
                              void* d_out, int out_size, void* d_ws, size_t ws_size,
                              hipStream_t stream) {
  const float* emb      = (const float*)d_in[0];
  const int*   nbr      = (const int*)d_in[1];
  const float* W1       = (const float*)d_in[2];
  const float* b1       = (const float*)d_in[3];
  const float* W2       = (const float*)d_in[4];
  const float* b2       = (const float*)d_in[5];
  const float* W3       = (const float*)d_in[6];
  const float* b3       = (const float*)d_in[7];
  const float* baseline = (const float*)d_in[8];
  float* out = (float*)d_out;

  char* ws = (char*)d_ws;
  float* g     = (float*)ws;                               // 2 KB
  float* plbuf = (float*)(ws + 2048);                      // 8192*260*4 B
  float* erbuf = (float*)(ws + 2048 + NV * RSTRIDE * 4);   // 8192*260*4 B
  float* part  = erbuf;  // alias: consumed by colmean_fin BEFORE mlp3h writes er
  unsigned* rawnu = (unsigned*)(ws + 2048);                // aliases dead pl rows
  double*   partd = (double*)(ws + 2048 + 65536);          // 2 KB

  colmean_part<<<64, 256, 0, stream>>>(emb, part);
  colmean_fin<<<1, 256, 0, stream>>>(part, g);
  mlp3h<<<NV / TV, 256, 0, stream>>>(emb, g, W1, b1, W2, b2, W3, b3, plbuf, erbuf);
  sortrows<<<NV / 4, 256, 0, stream>>>(plbuf);
  scan8<<<1, 128, 0, stream>>>(nbr, (const uint32_t*)plbuf, rawnu, out);
  logp_part<<<64, 256, 0, stream>>>((const float*)out, nbr, erbuf, rawnu, partd);
  finalize<<<1, 64, 0, stream>>>(partd, rawnu, baseline, out);
}

// Round 9
// 3024.365 us; speedup vs baseline: 2.3567x; 1.3119x over previous
//
#include <hip/hip_runtime.h>
#include <stdint.h>
#include <math.h>

#define NV 8192
#define EMB 512
#define CLS 257
#define DEG 32
#define TV 8
#define RSTRIDE 260   // padded row stride in floats (1040 B, 16B-aligned)

// ---------------------------------------------------------------------------
// Threefry-2x32, 20 rounds — exactly JAX's _threefry2x32. constexpr so the
// input-independent key chain (seed 42) can be baked in at compile time.
// ---------------------------------------------------------------------------
struct KP { uint32_t a, b; };

__host__ __device__ constexpr KP tfc(uint32_t k0, uint32_t k1,
                                     uint32_t x0, uint32_t x1) {
  const uint32_t ks2 = k0 ^ k1 ^ 0x1BD11BDAu;
  uint32_t v0 = x0 + k0, v1 = x1 + k1;
#define QR(r) { v0 += v1; v1 = (v1 << (r)) | (v1 >> (32 - (r))); v1 ^= v0; }
  QR(13) QR(15) QR(26) QR(6)
  v0 += k1;  v1 += ks2 + 1u;
  QR(17) QR(29) QR(16) QR(24)
  v0 += ks2; v1 += k0 + 2u;
  QR(13) QR(15) QR(26) QR(6)
  v0 += k0;  v1 += k1 + 3u;
  QR(17) QR(29) QR(16) QR(24)
  v0 += k1;  v1 += ks2 + 4u;
  QR(13) QR(15) QR(26) QR(6)
  v0 += ks2; v1 += k0 + 5u;
#undef QR
  return KP{v0, v1};
}

struct Seg { KP e[256]; };
constexpr Seg mkseg(KP s) {
  Seg g{};
  g.e[0] = s;
  for (int i = 1; i < 256; ++i) g.e[i] = tfc(g.e[i - 1].a, g.e[i - 1].b, 0u, 0u);
  return g;
}
#define NXTSEG(prev) mkseg(tfc(prev.e[255].a, prev.e[255].b, 0u, 0u))
constexpr Seg SG0 = mkseg(KP{0u, 42u});
constexpr Seg SG1 = NXTSEG(SG0);   constexpr Seg SG2 = NXTSEG(SG1);
constexpr Seg SG3 = NXTSEG(SG2);   constexpr Seg SG4 = NXTSEG(SG3);
constexpr Seg SG5 = NXTSEG(SG4);   constexpr Seg SG6 = NXTSEG(SG5);
constexpr Seg SG7 = NXTSEG(SG6);   constexpr Seg SG8 = NXTSEG(SG7);
constexpr Seg SG9 = NXTSEG(SG8);   constexpr Seg SG10 = NXTSEG(SG9);
constexpr Seg SG11 = NXTSEG(SG10); constexpr Seg SG12 = NXTSEG(SG11);
constexpr Seg SG13 = NXTSEG(SG12); constexpr Seg SG14 = NXTSEG(SG13);
constexpr Seg SG15 = NXTSEG(SG14); constexpr Seg SG16 = NXTSEG(SG15);
constexpr Seg SG17 = NXTSEG(SG16); constexpr Seg SG18 = NXTSEG(SG17);
constexpr Seg SG19 = NXTSEG(SG18); constexpr Seg SG20 = NXTSEG(SG19);
constexpr Seg SG21 = NXTSEG(SG20); constexpr Seg SG22 = NXTSEG(SG21);
constexpr Seg SG23 = NXTSEG(SG22); constexpr Seg SG24 = NXTSEG(SG23);
constexpr Seg SG25 = NXTSEG(SG24); constexpr Seg SG26 = NXTSEG(SG25);
constexpr Seg SG27 = NXTSEG(SG26); constexpr Seg SG28 = NXTSEG(SG27);
constexpr Seg SG29 = NXTSEG(SG28); constexpr Seg SG30 = NXTSEG(SG29);
constexpr Seg SG31 = NXTSEG(SG30);

struct KT { uint32_t hi[8192]; uint32_t lo[8192]; };
constexpr KT mkkt() {
  KT t{};
  const Seg* sg[32] = {
    &SG0,  &SG1,  &SG2,  &SG3,  &SG4,  &SG5,  &SG6,  &SG7,
    &SG8,  &SG9,  &SG10, &SG11, &SG12, &SG13, &SG14, &SG15,
    &SG16, &SG17, &SG18, &SG19, &SG20, &SG21, &SG22, &SG23,
    &SG24, &SG25, &SG26, &SG27, &SG28, &SG29, &SG30, &SG31 };
  for (int s = 0; s < 32; ++s)
    for (int i = 0; i < 256; ++i) {
      const int v = 1 + s * 256 + i;
      if (v < 8192) { t.hi[v] = sg[s]->e[i].a; t.lo[v] = sg[s]->e[i].b; }
    }
  return t;
}
__device__ const KT KEYS = mkkt();

// ---------------------------------------------------------------------------
// K1: graph_emb = mean(embeddings, axis=0)
// ---------------------------------------------------------------------------
__global__ __launch_bounds__(256) void colmean_part(const float* __restrict__ emb,
                                                    float* __restrict__ part) {
  const int b = blockIdx.x;
  const int t = threadIdx.x;
  for (int j = t; j < EMB; j += 256) {
    float s = 0.f;
    const int r0 = b * 128;
    for (int r = 0; r < 128; ++r) s += emb[(size_t)(r0 + r) * EMB + j];
    part[(size_t)b * EMB + j] = s;
  }
}

__global__ __launch_bounds__(256) void colmean_fin(const float* __restrict__ part,
                                                   float* __restrict__ g) {
  const int t = threadIdx.x;
  for (int j = t; j < EMB; j += 256) {
    float s = 0.f;
    for (int b = 0; b < 64; ++b) s += part[(size_t)b * EMB + j];
    g[j] = s / 8192.0f;
  }
}

// ---------------------------------------------------------------------------
// K2: fused 3-layer MLP, column-remapped + vectorized loads. Every
// (vertex,column) accumulator keeps the EXACT fmaf chain of rounds 1-8
// (kc-major, kk-ascending, chunk-local cacc then acc+=cacc) -> bit-identical
// logits. Thread t owns columns 2t,2t+1 in layers 1-2 (W rows loaded once
// per block, float2); xs/h1s/gs read as float4 from LDS.
// ---------------------------------------------------------------------------
__global__ __launch_bounds__(256) void mlp3i(
    const float* __restrict__ emb, const float* __restrict__ g,
    const float* __restrict__ W1, const float* __restrict__ b1,
    const float* __restrict__ W2, const float* __restrict__ b2,
    const float* __restrict__ W3, const float* __restrict__ b3,
    float* __restrict__ pl, float* __restrict__ er)
{
  __shared__ float xs[TV][68];
  __shared__ float gs[EMB];
  __shared__ float h1s[TV][EMB];     // 16 KB
  __shared__ float h2s[TV][400];     // 12.8 KB
  __shared__ float redw[TV][4];
  __shared__ float li256s[TV];
  __shared__ float mrs[TV];

  const int t  = threadIdx.x;
  const int v0 = blockIdx.x * TV;
  const int j2 = 2 * t;              // layer-1 columns j2, j2+1

  for (int j = t; j < EMB; j += 256) gs[j] = g[j];

  // ---- layer 1, emb half: cols (j2, j2+1) x 8 vertices ----
  float accA[TV], accB[TV];
#pragma unroll
  for (int vv = 0; vv < TV; ++vv) { accA[vv] = 0.f; accB[vv] = 0.f; }

  for (int kc = 0; kc < 8; ++kc) {
    __syncthreads();
    if (t < 128) {
      const int vv = t >> 4;
      const int kk = (t & 15) << 2;
      const float4 s4 = *reinterpret_cast<const float4*>(
          &emb[(size_t)(v0 + vv) * EMB + kc * 64 + kk]);
      xs[vv][kk] = s4.x; xs[vv][kk + 1] = s4.y;
      xs[vv][kk + 2] = s4.z; xs[vv][kk + 3] = s4.w;
    }
    __syncthreads();
    float cA[TV], cB[TV];
#pragma unroll
    for (int vv = 0; vv < TV; ++vv) { cA[vv] = 0.f; cB[vv] = 0.f; }
    for (int q = 0; q < 16; ++q) {
      const int k = kc * 64 + q * 4;
      float2 w[4];
#pragma unroll
      for (int u = 0; u < 4; ++u)
        w[u] = *reinterpret_cast<const float2*>(&W1[(size_t)(k + u) * EMB + j2]);
      float4 xv[TV];
#pragma unroll
      for (int vv = 0; vv < TV; ++vv)
        xv[vv] = *reinterpret_cast<const float4*>(&xs[vv][q * 4]);
#pragma unroll
      for (int u = 0; u < 4; ++u) {
#pragma unroll
        for (int vv = 0; vv < TV; ++vv) {
          const float x = (u == 0) ? xv[vv].x : (u == 1) ? xv[vv].y
                         : (u == 2) ? xv[vv].z : xv[vv].w;
          cA[vv] = fmaf(x, w[u].x, cA[vv]);
          cB[vv] = fmaf(x, w[u].y, cB[vv]);
        }
      }
    }
#pragma unroll
    for (int vv = 0; vv < TV; ++vv) { accA[vv] += cA[vv]; accB[vv] += cB[vv]; }
  }

  // ---- layer 1, graph_emb half for cols (j2, j2+1) ----
  float gA = 0.f, gB = 0.f;
  for (int kc = 0; kc < 8; ++kc) {
    float cgA = 0.f, cgB = 0.f;
    for (int q = 0; q < 16; ++q) {
      const int k = kc * 64 + q * 4;
      const float4 gv = *reinterpret_cast<const float4*>(&gs[k]);
      float2 w[4];
#pragma unroll
      for (int u = 0; u < 4; ++u)
        w[u] = *reinterpret_cast<const float2*>(
            &W1[(size_t)(EMB + k + u) * EMB + j2]);
      cgA = fmaf(gv.x, w[0].x, cgA); cgB = fmaf(gv.x, w[0].y, cgB);
      cgA = fmaf(gv.y, w[1].x, cgA); cgB = fmaf(gv.y, w[1].y, cgB);
      cgA = fmaf(gv.z, w[2].x, cgA); cgB = fmaf(gv.z, w[2].y, cgB);
      cgA = fmaf(gv.w, w[3].x, cgA); cgB = fmaf(gv.w, w[3].y, cgB);
    }
    gA += cgA; gB += cgB;
  }

  {
    const float bA = b1[j2], bB = b1[j2 + 1];
#pragma unroll
    for (int vv = 0; vv < TV; ++vv) {
      float hA = (accA[vv] + gA) + bA;
      float hB = (accB[vv] + gB) + bB;
      hA = (hA >= 0.f) ? hA : 0.01f * hA;
      hB = (hB >= 0.f) ? hB : 0.01f * hB;
      *reinterpret_cast<float2*>(&h1s[vv][j2]) = float2{hA, hB};
    }
  }
  __syncthreads();

  // ---- layer 2: cols (j2, j2+1) for t < 200, all 8 vertices ----
  if (t < 200) {
    float a2A[TV], a2B[TV];
#pragma unroll
    for (int vv = 0; vv < TV; ++vv) { a2A[vv] = 0.f; a2B[vv] = 0.f; }
    for (int kc = 0; kc < 8; ++kc) {
      float cA[TV], cB[TV];
#pragma unroll
      for (int vv = 0; vv < TV; ++vv) { cA[vv] = 0.f; cB[vv] = 0.f; }
      for (int q = 0; q < 16; ++q) {
        const int k = kc * 64 + q * 4;
        float2 w[4];
#pragma unroll
        for (int u = 0; u < 4; ++u)
          w[u] = *reinterpret_cast<const float2*>(&W2[(size_t)(k + u) * 400 + j2]);
        float4 hv[TV];
#pragma unroll
        for (int vv = 0; vv < TV; ++vv)
          hv[vv] = *reinterpret_cast<const float4*>(&h1s[vv][k]);
#pragma unroll
        for (int u = 0; u < 4; ++u) {
#pragma unroll
          for (int vv = 0; vv < TV; ++vv) {
            const float x = (u == 0) ? hv[vv].x : (u == 1) ? hv[vv].y
                           : (u == 2) ? hv[vv].z : hv[vv].w;
            cA[vv] = fmaf(x, w[u].x, cA[vv]);
            cB[vv] = fmaf(x, w[u].y, cB[vv]);
          }
        }
      }
#pragma unroll
      for (int vv = 0; vv < TV; ++vv) { a2A[vv] += cA[vv]; a2B[vv] += cB[vv]; }
    }
    const float bA = b2[j2], bB = b2[j2 + 1];
#pragma unroll
    for (int vv = 0; vv < TV; ++vv) {
      float hA = a2A[vv] + bA;
      float hB = a2B[vv] + bB;
      hA = (hA >= 0.f) ? hA : 0.01f * hA;
      hB = (hB >= 0.f) ? hB : 0.01f * hB;
      *reinterpret_cast<float2*>(&h2s[vv][j2]) = float2{hA, hB};
    }
  }
  __syncthreads();

  // ---- layer 3: class t (t==0 also handles class 256) — unchanged ----
  float a3[TV], a3x[TV];
#pragma unroll
  for (int vv = 0; vv < TV; ++vv) { a3[vv] = 0.f; a3x[vv] = 0.f; }
  for (int kc = 0; kc < 8; ++kc) {
    float c3[TV], c3x[TV];
#pragma unroll
    for (int vv = 0; vv < TV; ++vv) { c3[vv] = 0.f; c3x[vv] = 0.f; }
    for (int kk = 0; kk < 50; ++kk) {
      const int k = kc * 50 + kk;
      const float w0 = W3[(size_t)k * CLS + t];
      const float wx = (t == 0) ? W3[(size_t)k * CLS + 256] : 0.f;
#pragma unroll
      for (int vv = 0; vv < TV; ++vv) {
        const float hv = h2s[vv][k];
        c3[vv]  = fmaf(hv, w0, c3[vv]);
        c3x[vv] = fmaf(hv, wx, c3x[vv]);
      }
    }
#pragma unroll
    for (int vv = 0; vv < TV; ++vv) { a3[vv] += c3[vv]; a3x[vv] += c3x[vv]; }
  }

  const float bj = b3[t];
  float li_[TV];
#pragma unroll
  for (int vv = 0; vv < TV; ++vv) li_[vv] = a3[vv] + bj;

#pragma unroll
  for (int vv = 0; vv < TV; ++vv) {
    float m = li_[vv];
#pragma unroll
    for (int off = 1; off < 64; off <<= 1) m = fmaxf(m, __shfl_xor(m, off));
    if ((t & 63) == 0) redw[vv][t >> 6] = m;
  }
  if (t == 0) {
    const float bx = b3[256];
#pragma unroll
    for (int vv = 0; vv < TV; ++vv) li256s[vv] = a3x[vv] + bx;
  }
  __syncthreads();
  if (t < TV) {
    const float m = fmaxf(fmaxf(redw[t][0], redw[t][1]),
                          fmaxf(redw[t][2], redw[t][3]));
    mrs[t] = fmaxf(m, li256s[t]);
  }
  __syncthreads();

#pragma unroll
  for (int vv = 0; vv < TV; ++vv) {
    const int v = v0 + vv;
    const float li = li_[vv];
    const KP sk = tfc(KEYS.hi[v], KEYS.lo[v], 0u, 1u);
    const KP o  = tfc(sk.a, sk.b, 0u, (uint32_t)t);
    const uint32_t bb = o.a ^ o.b;
    const float f = __uint_as_float(0x3f800000u | (bb >> 9)) - 1.0f;
    const float u = fmaxf(1.17549435e-38f, f);
    const float gg = -logf(-logf(u));
    pl[(size_t)v * RSTRIDE + t] = li + gg;
    er[(size_t)v * RSTRIDE + t] = expf(li - mrs[vv]);
  }
  if (t == 0) {
    const float bx = b3[256];
#pragma unroll
    for (int vv = 0; vv < TV; ++vv) {
      const int v = v0 + vv;
      const float li = a3x[vv] + bx;
      const KP sk = tfc(KEYS.hi[v], KEYS.lo[v], 0u, 1u);
      const KP o  = tfc(sk.a, sk.b, 0u, 256u);
      const uint32_t bb = o.a ^ o.b;
      const float f = __uint_as_float(0x3f800000u | (bb >> 9)) - 1.0f;
      const float u = fmaxf(1.17549435e-38f, f);
      const float gg = -logf(-logf(u));
      pl[(size_t)v * RSTRIDE + 256] = li + gg;
      er[(size_t)v * RSTRIDE + 256] = expf(li - mrs[vv]);
    }
  }
}

// ---------------------------------------------------------------------------
// helpers
// ---------------------------------------------------------------------------
#define DPPF(CTRL, OLDI, X) \
  __builtin_amdgcn_update_dpp((int)(OLDI), (X), (CTRL), 0xF, 0xF, false)
#define SRED(CTRL) { S += __int_as_float(DPPF(CTRL, 0, __float_as_int(S))); }

__device__ __forceinline__ uint32_t ordmap(float f) {
  const uint32_t s = __float_as_uint(f);
  return s ^ (0x80000000u | (uint32_t)((int32_t)s >> 31));
}

#define WG_SCOPE __HIP_MEMORY_SCOPE_WORKGROUP

// ---------------------------------------------------------------------------
// K2b: per-row descending sort of 257 perturbed logits by (ordmap(pl), ~idx).
// First 320 u16 of each pl row overwritten IN PLACE with sorted class ids.
// ---------------------------------------------------------------------------
__global__ __launch_bounds__(256) void sortrows(float* __restrict__ plbuf) {
  __shared__ uint64_t keys[4][512];
  const int t = threadIdx.x;
  const int w = t >> 6;
  const int lane = t & 63;
  const int v = blockIdx.x * 4 + w;
  const float* row = plbuf + (size_t)v * RSTRIDE;

#pragma unroll
  for (int j = 0; j < 8; ++j) {
    const int i = lane + 64 * j;
    uint32_t om = 0u;
    if (i < CLS) om = ordmap(row[i]);
    keys[w][i] = ((uint64_t)om << 9) | (uint64_t)(511 - i);
  }
  __syncthreads();

  for (int k = 2; k <= 512; k <<= 1) {
    for (int j = k >> 1; j > 0; j >>= 1) {
#pragma unroll
      for (int m = 0; m < 4; ++m) {
        const int p  = lane + 64 * m;
        const int i  = ((p & ~(j - 1)) << 1) | (p & (j - 1));
        const int ix = i | j;
        const uint64_t a = keys[w][i], b = keys[w][ix];
        const bool sw = ((i & k) == 0) ? (a < b) : (a > b);
        if (sw) { keys[w][i] = b; keys[w][ix] = a; }
      }
      __syncthreads();
    }
  }

  uint16_t* o16 = reinterpret_cast<uint16_t*>(plbuf) + (size_t)v * (RSTRIDE * 2);
#pragma unroll
  for (int j = 0; j < 5; ++j) {
    const int i = lane + 64 * j;
    if (i < 320) o16[i] = (uint16_t)(511u - (uint32_t)(keys[w][i] & 511u));
  }
}

// ---------------------------------------------------------------------------
// K3: producer-consumer scan (scan5 structure) with top-128 fast path.
// Unchanged from round 8 (2422 us, best measured).
// ---------------------------------------------------------------------------
__global__ __launch_bounds__(128) void scan8(
    const int* __restrict__ nbrG, const uint32_t* __restrict__ scG,
    unsigned* __restrict__ rawnu, float* __restrict__ out)
{
  __shared__ int colors[NV];            // 32 KB
  __shared__ uint32_t scR[32][160];     // 20 KB ring: 320 u16 cands/row
  __shared__ int nbrRing[1024];         // 4 KB: 4 chunks x 8 rows x 32
  __shared__ unsigned bbuf[2][16];
  __shared__ int prod_done, cons_done;

  const int t = threadIdx.x;
  const int lane = t & 63;
  const int ln32 = lane & 31;
  const uint16_t* scR16 = reinterpret_cast<const uint16_t*>(&scR[0][0]);

  for (int i = t; i < NV; i += 128) colors[i] = -1;
  if (t == 0) { colors[0] = 0; prod_done = 0; cons_done = 0; }
  __syncthreads();

  if (t >= 64) {
    // ================= producer wave =================
    for (int pc = 0; pc < 1024; ++pc) {
      while (__hip_atomic_load(&cons_done, __ATOMIC_ACQUIRE, WG_SCOPE) < pc - 3)
        __builtin_amdgcn_s_sleep(1);
      uint32_t x[8], y[8], z[8];
#pragma unroll
      for (int r = 0; r < 8; ++r) {
        const size_t base = (size_t)(pc * 8 + r) * RSTRIDE;   // u32 units
        x[r] = scG[base + lane];
        y[r] = scG[base + 64 + lane];
        z[r] = (lane < 32) ? scG[base + 128 + lane] : 0u;
      }
      const int4 nb4 = *reinterpret_cast<const int4*>(nbrG + pc * 256 + 4 * lane);
#pragma unroll
      for (int r = 0; r < 8; ++r) {
        const int slot = (pc * 8 + r) & 31;
        scR[slot][lane] = x[r];
        scR[slot][64 + lane] = y[r];
        if (lane < 32) scR[slot][128 + lane] = z[r];
      }
      *reinterpret_cast<int4*>(&nbrRing[((pc & 3) << 8) + 4 * lane]) = nb4;
      if (lane == 0)
        __hip_atomic_store(&prod_done, pc + 1, __ATOMIC_RELEASE, WG_SCOPE);
    }
    return;
  }

  // ================= consumer wave =================
  while (__hip_atomic_load(&prod_done, __ATOMIC_ACQUIRE, WG_SCOPE) < 2) {}

  // prologue: state for v = 1
  int c0, c1;
  bool s0a, s0b, s1a, s1b, hf;
  int nbrn;
  {
    const int nb1 = nbrRing[32 + ln32];           // row 1, chunk 0
    bbuf[1][lane & 15] = 0u;
    hf = (__ballot(nb1 == 0) != 0ULL);
    const int cg0 = colors[nb1];
    if (cg0 >= 0) atomicOr(&bbuf[1][cg0 >> 5], 1u << (cg0 & 31));
    c0 = scR16[320 + lane];
    c1 = scR16[320 + 64 + lane];
    const unsigned w0 = bbuf[1][c0 >> 5];
    const unsigned w1 = bbuf[1][c1 >> 5];
    const bool f0 = !((w0 >> (c0 & 31)) & 1u);
    const bool f1 = !((w1 >> (c1 & 31)) & 1u);
    s0a = f0 && (c0 < 1 || c0 == 256);
    s0b = f0 && (c0 < 2 || c0 == 256);
    s1a = f1 && (c1 < 1 || c1 == 256);
    s1b = f1 && (c1 < 2 || c1 == 256);
    nbrn = nbrRing[64 + ln32];                    // row 2, chunk 0
  }

  int chosen_prev = 0;
  int n_used = 1;
  bool inP = false;   // did step v-1 allocate a new color?

  for (int v = 1; v < NV; ++v) {
    const int vp1 = (v + 1 < NV) ? v + 1 : NV - 1;
    const int vp2 = (v + 2 < NV) ? v + 2 : NV - 1;

    // ---- chunk sync (1/8 iters) ----
    if ((v & 7) == 7) {
      if (lane == 0)
        __hip_atomic_store(&cons_done, (v + 1) >> 3, __ATOMIC_RELEASE, WG_SCOPE);
      int tgt = ((v + 1) >> 3) + 2;
      tgt = tgt > 1024 ? 1024 : tgt;
      while (__hip_atomic_load(&prod_done, __ATOMIC_ACQUIRE, WG_SCOPE) < tgt) {}
    }

    // ---- prefetch phase: chunks 0-1 + mask for v+1 (both nu variants) ----
    const int sB = (vp1 & 31) * 320;
    const int n0 = scR16[sB + lane];
    const int n1 = scR16[sB + 64 + lane];
    const int nbrn2 = nbrRing[(((vp2 >> 3) & 3) << 8) + ((vp2 & 7) << 5) + ln32];

    const int nb = vp1 & 1;
    bbuf[nb][lane & 15] = 0u;
    const bool hfn = (__ballot(nbrn == v) != 0ULL);
    const int cgn = colors[nbrn];                 // stale gather (misses only v)
    if (cgn >= 0) atomicOr(&bbuf[nb][cgn >> 5], 1u << (cgn & 31));
    const unsigned wn0 = bbuf[nb][n0 >> 5];
    const unsigned wn1 = bbuf[nb][n1 >> 5];
    const int nuP = n_used;
    const bool fn0 = !((wn0 >> (n0 & 31)) & 1u);
    const bool fn1 = !((wn1 >> (n1 & 31)) & 1u);
    const bool sn0a = fn0 && (n0 < nuP || n0 == 256);
    const bool sn0b = fn0 && (n0 < nuP + 1 || n0 == 256);
    const bool sn1a = fn1 && (n1 < nuP || n1 == 256);
    const bool sn1b = fn1 && (n1 < nuP + 1 || n1 == 256);

    // ---- critical phase for v ----
    const int fixc = chosen_prev;
    int raw = 256;
    {
      const bool ok0 = (inP ? s0b : s0a) && !(hf && c0 == fixc);
      uint64_t b_ = __ballot(ok0);
      if (b_) {
        raw = __builtin_amdgcn_readlane(c0, (int)__builtin_ctzll(b_));
      } else {
        const bool ok1 = (inP ? s1b : s1a) && !(hf && c1 == fixc);
        b_ = __ballot(ok1);
        if (b_) {
          raw = __builtin_amdgcn_readlane(c1, (int)__builtin_ctzll(b_));
        } else {
          // slow path: chunks 2-4 of row v + ban slot v&1 (intact this iter)
          const int sBv = (v & 31) * 320;
          const int nu = n_used;
          const int x2 = scR16[sBv + 128 + lane];
          const int x3 = scR16[sBv + 192 + lane];
          const int x4 = scR16[sBv + 256 + lane];
          const unsigned q2 = bbuf[v & 1][x2 >> 5];
          const unsigned q3 = bbuf[v & 1][x3 >> 5];
          const unsigned q4 = bbuf[v & 1][x4 >> 5];
          const bool o2 = (!((q2 >> (x2 & 31)) & 1u)) &&
                          (x2 < nu || x2 == 256) && !(hf && x2 == fixc);
          const bool o3 = (!((q3 >> (x3 & 31)) & 1u)) &&
                          (x3 < nu || x3 == 256) && !(hf && x3 == fixc);
          const bool o4 = (!((q4 >> (x4 & 31)) & 1u)) &&
                          (x4 < nu || x4 == 256) && !(hf && x4 == fixc);
          if ((b_ = __ballot(o2)))
            raw = __builtin_amdgcn_readlane(x2, (int)__builtin_ctzll(b_));
          else if ((b_ = __ballot(o3)))
            raw = __builtin_amdgcn_readlane(x3, (int)__builtin_ctzll(b_));
          else if ((b_ = __ballot(o4)))
            raw = __builtin_amdgcn_readlane(x4, (int)__builtin_ctzll(b_));
        }
      }
    }

    const bool isnew = (raw == 256);
    const int chosen = isnew ? n_used : raw;
    if (lane == 0) {
      colors[v] = chosen;
      rawnu[v] = (unsigned)raw | ((unsigned)n_used << 16);
    }
    if (isnew) ++n_used;
    inP = isnew;
    chosen_prev = chosen;

    // ---- shift pipelined state ----
    c0 = n0; c1 = n1;
    s0a = sn0a; s0b = sn0b; s1a = sn1a; s1b = sn1b;
    hf = hfn; nbrn = nbrn2;
  }

  for (int i = lane; i < NV; i += 64) out[i] = (float)colors[i];
}

// ---------------------------------------------------------------------------
// K4: parallel logp recomputation (unchanged).
// ---------------------------------------------------------------------------
__global__ __launch_bounds__(256) void logp_part(
    const float* __restrict__ outF, const int* __restrict__ nbrG,
    const float* __restrict__ er, const unsigned* __restrict__ rawnu,
    double* __restrict__ partd)
{
  __shared__ unsigned bb[4][16];
  const int t = threadIdx.x;
  const int w = t >> 6;
  const int lane = t & 63;
  const int ln32 = lane & 31;
  const int b = blockIdx.x;

  double a = 0.0;
  for (int i = 0; i < 32; ++i) {
    const int v = b * 128 + w * 32 + i;
    if (v == 0) continue;
    const unsigned val = rawnu[v];
    const int raw = (int)(val & 0xFFFFu);
    const int nu  = (int)(val >> 16);

    bb[w][lane & 15] = 0u;
    const int u = nbrG[(size_t)v * DEG + ln32];
    const int cu = (u < v) ? (int)outF[u] : -1;
    if (cu >= 0) atomicOr(&bb[w][cu >> 5], 1u << (cu & 31));
    unsigned bwp[4];
#pragma unroll
    for (int j = 0; j < 4; ++j) bwp[j] = bb[w][(lane >> 5) + 2 * j];
    const unsigned bw8 = bb[w][8];

    const size_t base = (size_t)v * RSTRIDE;
    bool mk[4];
    float e[4];
#pragma unroll
    for (int j = 0; j < 4; ++j) {
      const int c = lane + 64 * j;
      mk[j] = (((bwp[j] >> ln32) & 1u) != 0u) || (c >= nu);
      e[j] = mk[j] ? 0.f : er[base + c];
    }
    const bool mkX = ((bw8 & 1u) != 0u);
    const float eX = er[base + 256];
    const float e4 = (!mkX && lane == 0) ? eX : 0.f;

    float S = ((e[0] + e[1]) + (e[2] + e[3])) + e4;
    SRED(0x111) SRED(0x112) SRED(0x114) SRED(0x118) SRED(0x142) SRED(0x143)
    const float Sall = __int_as_float(
        __builtin_amdgcn_readlane(__float_as_int(S), 63));

    const bool isnew = (raw == 256);
    const int jsel  = isnew ? 4 : (raw >> 6);
    const int owner = isnew ? 0 : (raw & 63);
    const float cand = (jsel == 0) ? e[0] : (jsel == 1) ? e[1]
                     : (jsel == 2) ? e[2] : (jsel == 3) ? e[3] : e4;
    const float praw = __int_as_float(
        __builtin_amdgcn_readlane(__float_as_int(cand), owner));

    const float p = praw / Sall;
    a += (double)(logf(p + 1e-8f) - logf(1e-8f));
  }
  if (lane == 0) partd[b * 4 + w] = a;
}

__global__ __launch_bounds__(64) void finalize(
    const double* __restrict__ partd, const unsigned* __restrict__ rawnu,
    const float* __restrict__ baseline, float* __restrict__ out)
{
  if (threadIdx.x == 0) {
    double lp = 0.0;
    for (int i = 0; i < 256; ++i) lp += partd[i];
    const unsigned val = rawnu[NV - 1];
    const unsigned nf = (val >> 16) + (((val & 0xFFFFu) == 256u) ? 1u : 0u);
    out[NV] = ((float)nf - baseline[0]) * (float)lp / 8192.0f;
  }
}

// ---------------------------------------------------------------------------
extern "C" void kernel_launch(void* const* d_in, const int* in_sizes, int n_in,
                              void* d_out, int out_size, void* d_ws, size_t ws_size,
                              hipStream_t stream) {
  const float* emb      = (const float*)d_in[0];
  const int*   nbr      = (const int*)d_in[1];
  const float* W1       = (const float*)d_in[2];
  const float* b1       = (const float*)d_in[3];
  const float* W2       = (const float*)d_in[4];
  const float* b2       = (const float*)d_in[5];
  const float* W3       = (const float*)d_in[6];
  const float* b3       = (const float*)d_in[7];
  const float* baseline = (const float*)d_in[8];
  float* out = (float*)d_out;

  char* ws = (char*)d_ws;
  float* g     = (float*)ws;                               // 2 KB
  float* plbuf = (float*)(ws + 2048);                      // 8192*260*4 B
  float* erbuf = (float*)(ws + 2048 + NV * RSTRIDE * 4);   // 8192*260*4 B
  float* part  = erbuf;  // alias: consumed by colmean_fin BEFORE mlp3i writes er
  unsigned* rawnu = (unsigned*)(ws + 2048);                // aliases dead pl rows
  double*   partd = (double*)(ws + 2048 + 65536);          // 2 KB

  colmean_part<<<64, 256, 0, stream>>>(emb, part);
  colmean_fin<<<1, 256, 0, stream>>>(part, g);
  mlp3i<<<NV / TV, 256, 0, stream>>>(emb, g, W1, b1, W2, b2, W3, b3, plbuf, erbuf);
  sortrows<<<NV / 4, 256, 0, stream>>>(plbuf);
  scan8<<<1, 128, 0, stream>>>(nbr, (const uint32_t*)plbuf, rawnu, out);
  logp_part<<<64, 256, 0, stream>>>((const float*)out, nbr, erbuf, rawnu, partd);
  finalize<<<1, 64, 0, stream>>>(partd, rawnu, baseline, out);
}

// Round 10
// 2907.310 us; speedup vs baseline: 2.4516x; 1.0403x over previous
//
#include <hip/hip_runtime.h>
#include <stdint.h>
#include <math.h>

#define NV 8192
#define EMB 512
#define CLS 257
#define DEG 32
#define TV 8
#define RSTRIDE 260   // padded row stride in floats (1040 B, 16B-aligned)

// ---------------------------------------------------------------------------
// Threefry-2x32, 20 rounds — exactly JAX's _threefry2x32. constexpr so the
// input-independent key chain (seed 42) can be baked in at compile time.
// ---------------------------------------------------------------------------
struct KP { uint32_t a, b; };

__host__ __device__ constexpr KP tfc(uint32_t k0, uint32_t k1,
                                     uint32_t x0, uint32_t x1) {
  const uint32_t ks2 = k0 ^ k1 ^ 0x1BD11BDAu;
  uint32_t v0 = x0 + k0, v1 = x1 + k1;
#define QR(r) { v0 += v1; v1 = (v1 << (r)) | (v1 >> (32 - (r))); v1 ^= v0; }
  QR(13) QR(15) QR(26) QR(6)
  v0 += k1;  v1 += ks2 + 1u;
  QR(17) QR(29) QR(16) QR(24)
  v0 += ks2; v1 += k0 + 2u;
  QR(13) QR(15) QR(26) QR(6)
  v0 += k0;  v1 += k1 + 3u;
  QR(17) QR(29) QR(16) QR(24)
  v0 += k1;  v1 += ks2 + 4u;
  QR(13) QR(15) QR(26) QR(6)
  v0 += ks2; v1 += k0 + 5u;
#undef QR
  return KP{v0, v1};
}

struct Seg { KP e[256]; };
constexpr Seg mkseg(KP s) {
  Seg g{};
  g.e[0] = s;
  for (int i = 1; i < 256; ++i) g.e[i] = tfc(g.e[i - 1].a, g.e[i - 1].b, 0u, 0u);
  return g;
}
#define NXTSEG(prev) mkseg(tfc(prev.e[255].a, prev.e[255].b, 0u, 0u))
constexpr Seg SG0 = mkseg(KP{0u, 42u});
constexpr Seg SG1 = NXTSEG(SG0);   constexpr Seg SG2 = NXTSEG(SG1);
constexpr Seg SG3 = NXTSEG(SG2);   constexpr Seg SG4 = NXTSEG(SG3);
constexpr Seg SG5 = NXTSEG(SG4);   constexpr Seg SG6 = NXTSEG(SG5);
constexpr Seg SG7 = NXTSEG(SG6);   constexpr Seg SG8 = NXTSEG(SG7);
constexpr Seg SG9 = NXTSEG(SG8);   constexpr Seg SG10 = NXTSEG(SG9);
constexpr Seg SG11 = NXTSEG(SG10); constexpr Seg SG12 = NXTSEG(SG11);
constexpr Seg SG13 = NXTSEG(SG12); constexpr Seg SG14 = NXTSEG(SG13);
constexpr Seg SG15 = NXTSEG(SG14); constexpr Seg SG16 = NXTSEG(SG15);
constexpr Seg SG17 = NXTSEG(SG16); constexpr Seg SG18 = NXTSEG(SG17);
constexpr Seg SG19 = NXTSEG(SG18); constexpr Seg SG20 = NXTSEG(SG19);
constexpr Seg SG21 = NXTSEG(SG20); constexpr Seg SG22 = NXTSEG(SG21);
constexpr Seg SG23 = NXTSEG(SG22); constexpr Seg SG24 = NXTSEG(SG23);
constexpr Seg SG25 = NXTSEG(SG24); constexpr Seg SG26 = NXTSEG(SG25);
constexpr Seg SG27 = NXTSEG(SG26); constexpr Seg SG28 = NXTSEG(SG27);
constexpr Seg SG29 = NXTSEG(SG28); constexpr Seg SG30 = NXTSEG(SG29);
constexpr Seg SG31 = NXTSEG(SG30);

struct KT { uint32_t hi[8192]; uint32_t lo[8192]; };
constexpr KT mkkt() {
  KT t{};
  const Seg* sg[32] = {
    &SG0,  &SG1,  &SG2,  &SG3,  &SG4,  &SG5,  &SG6,  &SG7,
    &SG8,  &SG9,  &SG10, &SG11, &SG12, &SG13, &SG14, &SG15,
    &SG16, &SG17, &SG18, &SG19, &SG20, &SG21, &SG22, &SG23,
    &SG24, &SG25, &SG26, &SG27, &SG28, &SG29, &SG30, &SG31 };
  for (int s = 0; s < 32; ++s)
    for (int i = 0; i < 256; ++i) {
      const int v = 1 + s * 256 + i;
      if (v < 8192) { t.hi[v] = sg[s]->e[i].a; t.lo[v] = sg[s]->e[i].b; }
    }
  return t;
}
__device__ const KT KEYS = mkkt();

// ---------------------------------------------------------------------------
// K1: graph_emb = mean(embeddings, axis=0)
// ---------------------------------------------------------------------------
__global__ __launch_bounds__(256) void colmean_part(const float* __restrict__ emb,
                                                    float* __restrict__ part) {
  const int b = blockIdx.x;
  const int t = threadIdx.x;
  for (int j = t; j < EMB; j += 256) {
    float s = 0.f;
    const int r0 = b * 128;
    for (int r = 0; r < 128; ++r) s += emb[(size_t)(r0 + r) * EMB + j];
    part[(size_t)b * EMB + j] = s;
  }
}

__global__ __launch_bounds__(256) void colmean_fin(const float* __restrict__ part,
                                                   float* __restrict__ g) {
  const int t = threadIdx.x;
  for (int j = t; j < EMB; j += 256) {
    float s = 0.f;
    for (int b = 0; b < 64; ++b) s += part[(size_t)b * EMB + j];
    g[j] = s / 8192.0f;
  }
}

// ---------------------------------------------------------------------------
// K2: fused 3-layer MLP, column-remapped + vectorized loads (round-9 mlp3i,
// bit-identical logits).
// ---------------------------------------------------------------------------
__global__ __launch_bounds__(256) void mlp3i(
    const float* __restrict__ emb, const float* __restrict__ g,
    const float* __restrict__ W1, const float* __restrict__ b1,
    const float* __restrict__ W2, const float* __restrict__ b2,
    const float* __restrict__ W3, const float* __restrict__ b3,
    float* __restrict__ pl, float* __restrict__ er)
{
  __shared__ float xs[TV][68];
  __shared__ float gs[EMB];
  __shared__ float h1s[TV][EMB];
  __shared__ float h2s[TV][400];
  __shared__ float redw[TV][4];
  __shared__ float li256s[TV];
  __shared__ float mrs[TV];

  const int t  = threadIdx.x;
  const int v0 = blockIdx.x * TV;
  const int j2 = 2 * t;

  for (int j = t; j < EMB; j += 256) gs[j] = g[j];

  float accA[TV], accB[TV];
#pragma unroll
  for (int vv = 0; vv < TV; ++vv) { accA[vv] = 0.f; accB[vv] = 0.f; }

  for (int kc = 0; kc < 8; ++kc) {
    __syncthreads();
    if (t < 128) {
      const int vv = t >> 4;
      const int kk = (t & 15) << 2;
      const float4 s4 = *reinterpret_cast<const float4*>(
          &emb[(size_t)(v0 + vv) * EMB + kc * 64 + kk]);
      xs[vv][kk] = s4.x; xs[vv][kk + 1] = s4.y;
      xs[vv][kk + 2] = s4.z; xs[vv][kk + 3] = s4.w;
    }
    __syncthreads();
    float cA[TV], cB[TV];
#pragma unroll
    for (int vv = 0; vv < TV; ++vv) { cA[vv] = 0.f; cB[vv] = 0.f; }
    for (int q = 0; q < 16; ++q) {
      const int k = kc * 64 + q * 4;
      float2 w[4];
#pragma unroll
      for (int u = 0; u < 4; ++u)
        w[u] = *reinterpret_cast<const float2*>(&W1[(size_t)(k + u) * EMB + j2]);
      float4 xv[TV];
#pragma unroll
      for (int vv = 0; vv < TV; ++vv)
        xv[vv] = *reinterpret_cast<const float4*>(&xs[vv][q * 4]);
#pragma unroll
      for (int u = 0; u < 4; ++u) {
#pragma unroll
        for (int vv = 0; vv < TV; ++vv) {
          const float x = (u == 0) ? xv[vv].x : (u == 1) ? xv[vv].y
                         : (u == 2) ? xv[vv].z : xv[vv].w;
          cA[vv] = fmaf(x, w[u].x, cA[vv]);
          cB[vv] = fmaf(x, w[u].y, cB[vv]);
        }
      }
    }
#pragma unroll
    for (int vv = 0; vv < TV; ++vv) { accA[vv] += cA[vv]; accB[vv] += cB[vv]; }
  }

  float gA = 0.f, gB = 0.f;
  for (int kc = 0; kc < 8; ++kc) {
    float cgA = 0.f, cgB = 0.f;
    for (int q = 0; q < 16; ++q) {
      const int k = kc * 64 + q * 4;
      const float4 gv = *reinterpret_cast<const float4*>(&gs[k]);
      float2 w[4];
#pragma unroll
      for (int u = 0; u < 4; ++u)
        w[u] = *reinterpret_cast<const float2*>(
            &W1[(size_t)(EMB + k + u) * EMB + j2]);
      cgA = fmaf(gv.x, w[0].x, cgA); cgB = fmaf(gv.x, w[0].y, cgB);
      cgA = fmaf(gv.y, w[1].x, cgA); cgB = fmaf(gv.y, w[1].y, cgB);
      cgA = fmaf(gv.z, w[2].x, cgA); cgB = fmaf(gv.z, w[2].y, cgB);
      cgA = fmaf(gv.w, w[3].x, cgA); cgB = fmaf(gv.w, w[3].y, cgB);
    }
    gA += cgA; gB += cgB;
  }

  {
    const float bA = b1[j2], bB = b1[j2 + 1];
#pragma unroll
    for (int vv = 0; vv < TV; ++vv) {
      float hA = (accA[vv] + gA) + bA;
      float hB = (accB[vv] + gB) + bB;
      hA = (hA >= 0.f) ? hA : 0.01f * hA;
      hB = (hB >= 0.f) ? hB : 0.01f * hB;
      *reinterpret_cast<float2*>(&h1s[vv][j2]) = float2{hA, hB};
    }
  }
  __syncthreads();

  if (t < 200) {
    float a2A[TV], a2B[TV];
#pragma unroll
    for (int vv = 0; vv < TV; ++vv) { a2A[vv] = 0.f; a2B[vv] = 0.f; }
    for (int kc = 0; kc < 8; ++kc) {
      float cA[TV], cB[TV];
#pragma unroll
      for (int vv = 0; vv < TV; ++vv) { cA[vv] = 0.f; cB[vv] = 0.f; }
      for (int q = 0; q < 16; ++q) {
        const int k = kc * 64 + q * 4;
        float2 w[4];
#pragma unroll
        for (int u = 0; u < 4; ++u)
          w[u] = *reinterpret_cast<const float2*>(&W2[(size_t)(k + u) * 400 + j2]);
        float4 hv[TV];
#pragma unroll
        for (int vv = 0; vv < TV; ++vv)
          hv[vv] = *reinterpret_cast<const float4*>(&h1s[vv][k]);
#pragma unroll
        for (int u = 0; u < 4; ++u) {
#pragma unroll
          for (int vv = 0; vv < TV; ++vv) {
            const float x = (u == 0) ? hv[vv].x : (u == 1) ? hv[vv].y
                           : (u == 2) ? hv[vv].z : hv[vv].w;
            cA[vv] = fmaf(x, w[u].x, cA[vv]);
            cB[vv] = fmaf(x, w[u].y, cB[vv]);
          }
        }
      }
#pragma unroll
      for (int vv = 0; vv < TV; ++vv) { a2A[vv] += cA[vv]; a2B[vv] += cB[vv]; }
    }
    const float bA = b2[j2], bB = b2[j2 + 1];
#pragma unroll
    for (int vv = 0; vv < TV; ++vv) {
      float hA = a2A[vv] + bA;
      float hB = a2B[vv] + bB;
      hA = (hA >= 0.f) ? hA : 0.01f * hA;
      hB = (hB >= 0.f) ? hB : 0.01f * hB;
      *reinterpret_cast<float2*>(&h2s[vv][j2]) = float2{hA, hB};
    }
  }
  __syncthreads();

  float a3[TV], a3x[TV];
#pragma unroll
  for (int vv = 0; vv < TV; ++vv) { a3[vv] = 0.f; a3x[vv] = 0.f; }
  for (int kc = 0; kc < 8; ++kc) {
    float c3[TV], c3x[TV];
#pragma unroll
    for (int vv = 0; vv < TV; ++vv) { c3[vv] = 0.f; c3x[vv] = 0.f; }
    for (int kk = 0; kk < 50; ++kk) {
      const int k = kc * 50 + kk;
      const float w0 = W3[(size_t)k * CLS + t];
      const float wx = (t == 0) ? W3[(size_t)k * CLS + 256] : 0.f;
#pragma unroll
      for (int vv = 0; vv < TV; ++vv) {
        const float hv = h2s[vv][k];
        c3[vv]  = fmaf(hv, w0, c3[vv]);
        c3x[vv] = fmaf(hv, wx, c3x[vv]);
      }
    }
#pragma unroll
    for (int vv = 0; vv < TV; ++vv) { a3[vv] += c3[vv]; a3x[vv] += c3x[vv]; }
  }

  const float bj = b3[t];
  float li_[TV];
#pragma unroll
  for (int vv = 0; vv < TV; ++vv) li_[vv] = a3[vv] + bj;

#pragma unroll
  for (int vv = 0; vv < TV; ++vv) {
    float m = li_[vv];
#pragma unroll
    for (int off = 1; off < 64; off <<= 1) m = fmaxf(m, __shfl_xor(m, off));
    if ((t & 63) == 0) redw[vv][t >> 6] = m;
  }
  if (t == 0) {
    const float bx = b3[256];
#pragma unroll
    for (int vv = 0; vv < TV; ++vv) li256s[vv] = a3x[vv] + bx;
  }
  __syncthreads();
  if (t < TV) {
    const float m = fmaxf(fmaxf(redw[t][0], redw[t][1]),
                          fmaxf(redw[t][2], redw[t][3]));
    mrs[t] = fmaxf(m, li256s[t]);
  }
  __syncthreads();

#pragma unroll
  for (int vv = 0; vv < TV; ++vv) {
    const int v = v0 + vv;
    const float li = li_[vv];
    const KP sk = tfc(KEYS.hi[v], KEYS.lo[v], 0u, 1u);
    const KP o  = tfc(sk.a, sk.b, 0u, (uint32_t)t);
    const uint32_t bb = o.a ^ o.b;
    const float f = __uint_as_float(0x3f800000u | (bb >> 9)) - 1.0f;
    const float u = fmaxf(1.17549435e-38f, f);
    const float gg = -logf(-logf(u));
    pl[(size_t)v * RSTRIDE + t] = li + gg;
    er[(size_t)v * RSTRIDE + t] = expf(li - mrs[vv]);
  }
  if (t == 0) {
    const float bx = b3[256];
#pragma unroll
    for (int vv = 0; vv < TV; ++vv) {
      const int v = v0 + vv;
      const float li = a3x[vv] + bx;
      const KP sk = tfc(KEYS.hi[v], KEYS.lo[v], 0u, 1u);
      const KP o  = tfc(sk.a, sk.b, 0u, 256u);
      const uint32_t bb = o.a ^ o.b;
      const float f = __uint_as_float(0x3f800000u | (bb >> 9)) - 1.0f;
      const float u = fmaxf(1.17549435e-38f, f);
      const float gg = -logf(-logf(u));
      pl[(size_t)v * RSTRIDE + 256] = li + gg;
      er[(size_t)v * RSTRIDE + 256] = expf(li - mrs[vv]);
    }
  }
}

// ---------------------------------------------------------------------------
// helpers
// ---------------------------------------------------------------------------
#define DPPF(CTRL, OLDI, X) \
  __builtin_amdgcn_update_dpp((int)(OLDI), (X), (CTRL), 0xF, 0xF, false)
#define SRED(CTRL) { S += __int_as_float(DPPF(CTRL, 0, __float_as_int(S))); }

__device__ __forceinline__ uint32_t ordmap(float f) {
  const uint32_t s = __float_as_uint(f);
  return s ^ (0x80000000u | (uint32_t)((int32_t)s >> 31));
}

#define WG_SCOPE __HIP_MEMORY_SCOPE_WORKGROUP

// ---------------------------------------------------------------------------
// K2b: per-row descending sort of 257 perturbed logits by (ordmap(pl), ~idx).
// First 320 u16 of each pl row overwritten IN PLACE with sorted class ids.
// ---------------------------------------------------------------------------
__global__ __launch_bounds__(256) void sortrows(float* __restrict__ plbuf) {
  __shared__ uint64_t keys[4][512];
  const int t = threadIdx.x;
  const int w = t >> 6;
  const int lane = t & 63;
  const int v = blockIdx.x * 4 + w;
  const float* row = plbuf + (size_t)v * RSTRIDE;

#pragma unroll
  for (int j = 0; j < 8; ++j) {
    const int i = lane + 64 * j;
    uint32_t om = 0u;
    if (i < CLS) om = ordmap(row[i]);
    keys[w][i] = ((uint64_t)om << 9) | (uint64_t)(511 - i);
  }
  __syncthreads();

  for (int k = 2; k <= 512; k <<= 1) {
    for (int j = k >> 1; j > 0; j >>= 1) {
#pragma unroll
      for (int m = 0; m < 4; ++m) {
        const int p  = lane + 64 * m;
        const int i  = ((p & ~(j - 1)) << 1) | (p & (j - 1));
        const int ix = i | j;
        const uint64_t a = keys[w][i], b = keys[w][ix];
        const bool sw = ((i & k) == 0) ? (a < b) : (a > b);
        if (sw) { keys[w][i] = b; keys[w][ix] = a; }
      }
      __syncthreads();
    }
  }

  uint16_t* o16 = reinterpret_cast<uint16_t*>(plbuf) + (size_t)v * (RSTRIDE * 2);
#pragma unroll
  for (int j = 0; j < 5; ++j) {
    const int i = lane + 64 * j;
    if (i < 320) o16[i] = (uint16_t)(511u - (uint32_t)(keys[w][i] & 511u));
  }
}

// ---------------------------------------------------------------------------
// K3: scan9 — scan8 semantics, re-scheduled so every LDS op's address is a
// loop-carried register: packed b32 candidates loaded 2 iters ahead;
// zero/atomicOr/readback issued BEFORE critical (operands from last iter);
// s-bits computed after critical with exact n_used; gather for v+2 after
// colors[v] write (single hf fix, same as scan8); sync at end of iter.
// ---------------------------------------------------------------------------
__global__ __launch_bounds__(128) void scan9(
    const int* __restrict__ nbrG, const uint32_t* __restrict__ scG,
    unsigned* __restrict__ rawnu, float* __restrict__ out)
{
  __shared__ int colors[NV];            // 32 KB
  __shared__ uint32_t scR[32][160];     // 20 KB ring: 320 u16 cands/row
  __shared__ int nbrRing[1024];         // 4 KB: 4 chunks x 8 rows x 32
  __shared__ unsigned bbuf[2][16];
  __shared__ int prod_done, cons_done;

  const int t = threadIdx.x;
  const int lane = t & 63;
  const int ln32 = lane & 31;
  const uint16_t* scR16 = reinterpret_cast<const uint16_t*>(&scR[0][0]);

  for (int i = t; i < NV; i += 128) colors[i] = -1;
  if (t == 0) { colors[0] = 0; prod_done = 0; cons_done = 0; }
  __syncthreads();

  if (t >= 64) {
    // ================= producer wave =================
    for (int pc = 0; pc < 1024; ++pc) {
      while (__hip_atomic_load(&cons_done, __ATOMIC_ACQUIRE, WG_SCOPE) < pc - 3)
        __builtin_amdgcn_s_sleep(1);
      uint32_t x[8], y[8], z[8];
#pragma unroll
      for (int r = 0; r < 8; ++r) {
        const size_t base = (size_t)(pc * 8 + r) * RSTRIDE;   // u32 units
        x[r] = scG[base + lane];
        y[r] = scG[base + 64 + lane];
        z[r] = (lane < 32) ? scG[base + 128 + lane] : 0u;
      }
      const int4 nb4 = *reinterpret_cast<const int4*>(nbrG + pc * 256 + 4 * lane);
#pragma unroll
      for (int r = 0; r < 8; ++r) {
        const int slot = (pc * 8 + r) & 31;
        scR[slot][lane] = x[r];
        scR[slot][64 + lane] = y[r];
        if (lane < 32) scR[slot][128 + lane] = z[r];
      }
      *reinterpret_cast<int4*>(&nbrRing[((pc & 3) << 8) + 4 * lane]) = nb4;
      if (lane == 0)
        __hip_atomic_store(&prod_done, pc + 1, __ATOMIC_RELEASE, WG_SCOPE);
    }
    return;
  }

  // ================= consumer wave =================
  while (__hip_atomic_load(&prod_done, __ATOMIC_ACQUIRE, WG_SCOPE) < 2) {}

  int cp1 = 0;        // chosen(v-1)
  int n_used = 1;

  // ---- prologue: prime state for v = 1 ----
  int c0, c1, d0, d1;
  bool sb0, sb1, hf;
  int nbrA, nbrB, cgv1;
  {
    // row 1: complete mask (colors[0] present), nu = 1
    bbuf[1][lane & 15] = 0u;
    const int nb1 = nbrRing[(1 << 5) + ln32];
    const int cg = colors[nb1];
    if (cg >= 0) atomicOr(&bbuf[1][cg >> 5], 1u << (cg & 31));
    const uint32_t cw = scR[1][lane];
    c0 = (int)(cw & 0xFFFFu); c1 = (int)(cw >> 16);
    const unsigned w0 = bbuf[1][c0 >> 5];
    const unsigned w1 = bbuf[1][c1 >> 5];
    sb0 = (!((w0 >> (c0 & 31)) & 1u)) && (c0 < 1 || c0 == 256);
    sb1 = (!((w1 >> (c1 & 31)) & 1u)) && (c1 < 1 || c1 == 256);
    hf = false;
    // row 2 pending
    const uint32_t dw = scR[2][lane];
    d0 = (int)(dw & 0xFFFFu); d1 = (int)(dw >> 16);
    nbrA = nbrRing[(2 << 5) + ln32];   // nbr row 2
    cgv1 = colors[nbrA];               // content <= colors[0]
    nbrB = nbrRing[(3 << 5) + ln32];   // nbr row 3
  }

  for (int v = 1; v < NV; ++v) {
    const int slotN = (v + 1) & 1;

    // ---- issue-only LDS phase (all operands in regs) ----
    bbuf[slotN][lane & 15] = 0u;
    if (cgv1 >= 0) atomicOr(&bbuf[slotN][cgv1 >> 5], 1u << (cgv1 & 31));
    const unsigned wd0 = bbuf[slotN][d0 >> 5];
    const unsigned wd1 = bbuf[slotN][d1 >> 5];

    // ---- critical phase for v ----
    const int nu0 = n_used;
    const int fixc = cp1;
    int raw = 256;
    {
      const bool okE = sb0 && !(hf && c0 == fixc);
      const bool okO = sb1 && !(hf && c1 == fixc);
      uint64_t b_ = __ballot(okE || okO);
      if (b_) {
        const int sel = okE ? c0 : c1;
        raw = __builtin_amdgcn_readlane(sel, (int)__builtin_ctzll(b_));
      } else {
        // slow path: ranks 128..319 of row v; ban slot v&1 intact this iter
        const int sBv = (v & 31) * 320;
        const int x2 = scR16[sBv + 128 + lane];
        const int x3 = scR16[sBv + 192 + lane];
        const int x4 = scR16[sBv + 256 + lane];
        const unsigned q2 = bbuf[v & 1][x2 >> 5];
        const unsigned q3 = bbuf[v & 1][x3 >> 5];
        const unsigned q4 = bbuf[v & 1][x4 >> 5];
        const bool o2 = (!((q2 >> (x2 & 31)) & 1u)) &&
                        (x2 < nu0 || x2 == 256) && !(hf && x2 == fixc);
        const bool o3 = (!((q3 >> (x3 & 31)) & 1u)) &&
                        (x3 < nu0 || x3 == 256) && !(hf && x3 == fixc);
        const bool o4 = (!((q4 >> (x4 & 31)) & 1u)) &&
                        (x4 < nu0 || x4 == 256) && !(hf && x4 == fixc);
        if ((b_ = __ballot(o2)))
          raw = __builtin_amdgcn_readlane(x2, (int)__builtin_ctzll(b_));
        else if ((b_ = __ballot(o3)))
          raw = __builtin_amdgcn_readlane(x3, (int)__builtin_ctzll(b_));
        else if ((b_ = __ballot(o4)))
          raw = __builtin_amdgcn_readlane(x4, (int)__builtin_ctzll(b_));
      }
    }
    const bool isnew = (raw == 256);
    const int chosen = isnew ? nu0 : raw;
    if (lane == 0) {
      colors[v] = chosen;
      rawnu[v] = (unsigned)raw | ((unsigned)nu0 << 16);
    }
    if (isnew) ++n_used;
    cp1 = chosen;

    // ---- s-bits for row v+1 (exact nu; wd latency covered by critical) ----
    const int nuN = n_used;
    const bool sbn0 = (!((wd0 >> (d0 & 31)) & 1u)) && (d0 < nuN || d0 == 256);
    const bool sbn1 = (!((wd1 >> (d1 & 31)) & 1u)) && (d1 < nuN || d1 == 256);
    const bool hfn = (__ballot(nbrA == v) != 0ULL);

    // ---- gather for row v+2 (after colors[v] write -> content <= v) ----
    const int cgv2 = colors[nbrB];

    // ---- loads for rows v+2 (cands) and v+3 (nbr) ----
    const int vp2 = (v + 2 < NV) ? v + 2 : NV - 1;
    const int vp3 = (v + 3 < NV) ? v + 3 : NV - 1;
    const uint32_t ew = scR[vp2 & 31][lane];
    const int nbrC = nbrRing[(((vp3 >> 3) & 3) << 8) + ((vp3 & 7) << 5) + ln32];

    // ---- shift pipelined state ----
    c0 = d0; c1 = d1; sb0 = sbn0; sb1 = sbn1; hf = hfn;
    d0 = (int)(ew & 0xFFFFu); d1 = (int)(ew >> 16);
    cgv1 = cgv2; nbrA = nbrB; nbrB = nbrC;

    // ---- chunk sync at END of iter (row v fully consumed) ----
    if ((v & 7) == 7) {
      if (lane == 0)
        __hip_atomic_store(&cons_done, (v + 1) >> 3, __ATOMIC_RELEASE, WG_SCOPE);
      int tgt = ((v + 1) >> 3) + 2;
      tgt = tgt > 1024 ? 1024 : tgt;
      while (__hip_atomic_load(&prod_done, __ATOMIC_ACQUIRE, WG_SCOPE) < tgt) {}
    }
  }

  for (int i = lane; i < NV; i += 64) out[i] = (float)colors[i];
}

// ---------------------------------------------------------------------------
// K4: parallel logp recomputation (unchanged).
// ---------------------------------------------------------------------------
__global__ __launch_bounds__(256) void logp_part(
    const float* __restrict__ outF, const int* __restrict__ nbrG,
    const float* __restrict__ er, const unsigned* __restrict__ rawnu,
    double* __restrict__ partd)
{
  __shared__ unsigned bb[4][16];
  const int t = threadIdx.x;
  const int w = t >> 6;
  const int lane = t & 63;
  const int ln32 = lane & 31;
  const int b = blockIdx.x;

  double a = 0.0;
  for (int i = 0; i < 32; ++i) {
    const int v = b * 128 + w * 32 + i;
    if (v == 0) continue;
    const unsigned val = rawnu[v];
    const int raw = (int)(val & 0xFFFFu);
    const int nu  = (int)(val >> 16);

    bb[w][lane & 15] = 0u;
    const int u = nbrG[(size_t)v * DEG + ln32];
    const int cu = (u < v) ? (int)outF[u] : -1;
    if (cu >= 0) atomicOr(&bb[w][cu >> 5], 1u << (cu & 31));
    unsigned bwp[4];
#pragma unroll
    for (int j = 0; j < 4; ++j) bwp[j] = bb[w][(lane >> 5) + 2 * j];
    const unsigned bw8 = bb[w][8];

    const size_t base = (size_t)v * RSTRIDE;
    bool mk[4];
    float e[4];
#pragma unroll
    for (int j = 0; j < 4; ++j) {
      const int c = lane + 64 * j;
      mk[j] = (((bwp[j] >> ln32) & 1u) != 0u) || (c >= nu);
      e[j] = mk[j] ? 0.f : er[base + c];
    }
    const bool mkX = ((bw8 & 1u) != 0u);
    const float eX = er[base + 256];
    const float e4 = (!mkX && lane == 0) ? eX : 0.f;

    float S = ((e[0] + e[1]) + (e[2] + e[3])) + e4;
    SRED(0x111) SRED(0x112) SRED(0x114) SRED(0x118) SRED(0x142) SRED(0x143)
    const float Sall = __int_as_float(
        __builtin_amdgcn_readlane(__float_as_int(S), 63));

    const bool isnew = (raw == 256);
    const int jsel  = isnew ? 4 : (raw >> 6);
    const int owner = isnew ? 0 : (raw & 63);
    const float cand = (jsel == 0) ? e[0] : (jsel == 1) ? e[1]
                     : (jsel == 2) ? e[2] : (jsel == 3) ? e[3] : e4;
    const float praw = __int_as_float(
        __builtin_amdgcn_readlane(__float_as_int(cand), owner));

    const float p = praw / Sall;
    a += (double)(logf(p + 1e-8f) - logf(1e-8f));
  }
  if (lane == 0) partd[b * 4 + w] = a;
}

__global__ __launch_bounds__(64) void finalize(
    const double* __restrict__ partd, const unsigned* __restrict__ rawnu,
    const float* __restrict__ baseline, float* __restrict__ out)
{
  if (threadIdx.x == 0) {
    double lp = 0.0;
    for (int i = 0; i < 256; ++i) lp += partd[i];
    const unsigned val = rawnu[NV - 1];
    const unsigned nf = (val >> 16) + (((val & 0xFFFFu) == 256u) ? 1u : 0u);
    out[NV] = ((float)nf - baseline[0]) * (float)lp / 8192.0f;
  }
}

// ---------------------------------------------------------------------------
extern "C" void kernel_launch(void* const* d_in, const int* in_sizes, int n_in,
                              void* d_out, int out_size, void* d_ws, size_t ws_size,
                              hipStream_t stream) {
  const float* emb      = (const float*)d_in[0];
  const int*   nbr      = (const int*)d_in[1];
  const float* W1       = (const float*)d_in[2];
  const float* b1       = (const float*)d_in[3];
  const float* W2       = (const float*)d_in[4];
  const float* b2       = (const float*)d_in[5];
  const float* W3       = (const float*)d_in[6];
  const float* b3       = (const float*)d_in[7];
  const float* baseline = (const float*)d_in[8];
  float* out = (float*)d_out;

  char* ws = (char*)d_ws;
  float* g     = (float*)ws;                               // 2 KB
  float* plbuf = (float*)(ws + 2048);                      // 8192*260*4 B
  float* erbuf = (float*)(ws + 2048 + NV * RSTRIDE * 4);   // 8192*260*4 B
  float* part  = erbuf;  // alias: consumed by colmean_fin BEFORE mlp3i writes er
  unsigned* rawnu = (unsigned*)(ws + 2048);                // aliases dead pl rows
  double*   partd = (double*)(ws + 2048 + 65536);          // 2 KB

  colmean_part<<<64, 256, 0, stream>>>(emb, part);
  colmean_fin<<<1, 256, 0, stream>>>(part, g);
  mlp3i<<<NV / TV, 256, 0, stream>>>(emb, g, W1, b1, W2, b2, W3, b3, plbuf, erbuf);
  sortrows<<<NV / 4, 256, 0, stream>>>(plbuf);
  scan9<<<1, 128, 0, stream>>>(nbr, (const uint32_t*)plbuf, rawnu, out);
  logp_part<<<64, 256, 0, stream>>>((const float*)out, nbr, erbuf, rawnu, partd);
  finalize<<<1, 64, 0, stream>>>(partd, rawnu, baseline, out);
}

// Round 11
// 2514.216 us; speedup vs baseline: 2.8349x; 1.1563x over previous
//
#include <hip/hip_runtime.h>
#include <stdint.h>
#include <math.h>

#define NV 8192
#define EMB 512
#define CLS 257
#define DEG 32
#define TV 8
#define RSTRIDE 260   // padded row stride in floats (1040 B, 16B-aligned)

// ---------------------------------------------------------------------------
// Threefry-2x32, 20 rounds — exactly JAX's _threefry2x32. constexpr so the
// input-independent key chain (seed 42) can be baked in at compile time.
// ---------------------------------------------------------------------------
struct KP { uint32_t a, b; };

__host__ __device__ constexpr KP tfc(uint32_t k0, uint32_t k1,
                                     uint32_t x0, uint32_t x1) {
  const uint32_t ks2 = k0 ^ k1 ^ 0x1BD11BDAu;
  uint32_t v0 = x0 + k0, v1 = x1 + k1;
#define QR(r) { v0 += v1; v1 = (v1 << (r)) | (v1 >> (32 - (r))); v1 ^= v0; }
  QR(13) QR(15) QR(26) QR(6)
  v0 += k1;  v1 += ks2 + 1u;
  QR(17) QR(29) QR(16) QR(24)
  v0 += ks2; v1 += k0 + 2u;
  QR(13) QR(15) QR(26) QR(6)
  v0 += k0;  v1 += k1 + 3u;
  QR(17) QR(29) QR(16) QR(24)
  v0 += k1;  v1 += ks2 + 4u;
  QR(13) QR(15) QR(26) QR(6)
  v0 += ks2; v1 += k0 + 5u;
#undef QR
  return KP{v0, v1};
}

struct Seg { KP e[256]; };
constexpr Seg mkseg(KP s) {
  Seg g{};
  g.e[0] = s;
  for (int i = 1; i < 256; ++i) g.e[i] = tfc(g.e[i - 1].a, g.e[i - 1].b, 0u, 0u);
  return g;
}
#define NXTSEG(prev) mkseg(tfc(prev.e[255].a, prev.e[255].b, 0u, 0u))
constexpr Seg SG0 = mkseg(KP{0u, 42u});
constexpr Seg SG1 = NXTSEG(SG0);   constexpr Seg SG2 = NXTSEG(SG1);
constexpr Seg SG3 = NXTSEG(SG2);   constexpr Seg SG4 = NXTSEG(SG3);
constexpr Seg SG5 = NXTSEG(SG4);   constexpr Seg SG6 = NXTSEG(SG5);
constexpr Seg SG7 = NXTSEG(SG6);   constexpr Seg SG8 = NXTSEG(SG7);
constexpr Seg SG9 = NXTSEG(SG8);   constexpr Seg SG10 = NXTSEG(SG9);
constexpr Seg SG11 = NXTSEG(SG10); constexpr Seg SG12 = NXTSEG(SG11);
constexpr Seg SG13 = NXTSEG(SG12); constexpr Seg SG14 = NXTSEG(SG13);
constexpr Seg SG15 = NXTSEG(SG14); constexpr Seg SG16 = NXTSEG(SG15);
constexpr Seg SG17 = NXTSEG(SG16); constexpr Seg SG18 = NXTSEG(SG17);
constexpr Seg SG19 = NXTSEG(SG18); constexpr Seg SG20 = NXTSEG(SG19);
constexpr Seg SG21 = NXTSEG(SG20); constexpr Seg SG22 = NXTSEG(SG21);
constexpr Seg SG23 = NXTSEG(SG22); constexpr Seg SG24 = NXTSEG(SG23);
constexpr Seg SG25 = NXTSEG(SG24); constexpr Seg SG26 = NXTSEG(SG25);
constexpr Seg SG27 = NXTSEG(SG26); constexpr Seg SG28 = NXTSEG(SG27);
constexpr Seg SG29 = NXTSEG(SG28); constexpr Seg SG30 = NXTSEG(SG29);
constexpr Seg SG31 = NXTSEG(SG30);

struct KT { uint32_t hi[8192]; uint32_t lo[8192]; };
constexpr KT mkkt() {
  KT t{};
  const Seg* sg[32] = {
    &SG0,  &SG1,  &SG2,  &SG3,  &SG4,  &SG5,  &SG6,  &SG7,
    &SG8,  &SG9,  &SG10, &SG11, &SG12, &SG13, &SG14, &SG15,
    &SG16, &SG17, &SG18, &SG19, &SG20, &SG21, &SG22, &SG23,
    &SG24, &SG25, &SG26, &SG27, &SG28, &SG29, &SG30, &SG31 };
  for (int s = 0; s < 32; ++s)
    for (int i = 0; i < 256; ++i) {
      const int v = 1 + s * 256 + i;
      if (v < 8192) { t.hi[v] = sg[s]->e[i].a; t.lo[v] = sg[s]->e[i].b; }
    }
  return t;
}
__device__ const KT KEYS = mkkt();

// ---------------------------------------------------------------------------
// K1: graph_emb = mean(embeddings, axis=0)
// ---------------------------------------------------------------------------
__global__ __launch_bounds__(256) void colmean_part(const float* __restrict__ emb,
                                                    float* __restrict__ part) {
  const int b = blockIdx.x;
  const int t = threadIdx.x;
  for (int j = t; j < EMB; j += 256) {
    float s = 0.f;
    const int r0 = b * 128;
    for (int r = 0; r < 128; ++r) s += emb[(size_t)(r0 + r) * EMB + j];
    part[(size_t)b * EMB + j] = s;
  }
}

__global__ __launch_bounds__(256) void colmean_fin(const float* __restrict__ part,
                                                   float* __restrict__ g) {
  const int t = threadIdx.x;
  for (int j = t; j < EMB; j += 256) {
    float s = 0.f;
    for (int b = 0; b < 64; ++b) s += part[(size_t)b * EMB + j];
    g[j] = s / 8192.0f;
  }
}

// ---------------------------------------------------------------------------
// K2: fused 3-layer MLP, column-remapped + vectorized loads (round-9 mlp3i,
// bit-identical logits).
// ---------------------------------------------------------------------------
__global__ __launch_bounds__(256) void mlp3i(
    const float* __restrict__ emb, const float* __restrict__ g,
    const float* __restrict__ W1, const float* __restrict__ b1,
    const float* __restrict__ W2, const float* __restrict__ b2,
    const float* __restrict__ W3, const float* __restrict__ b3,
    float* __restrict__ pl, float* __restrict__ er)
{
  __shared__ float xs[TV][68];
  __shared__ float gs[EMB];
  __shared__ float h1s[TV][EMB];
  __shared__ float h2s[TV][400];
  __shared__ float redw[TV][4];
  __shared__ float li256s[TV];
  __shared__ float mrs[TV];

  const int t  = threadIdx.x;
  const int v0 = blockIdx.x * TV;
  const int j2 = 2 * t;

  for (int j = t; j < EMB; j += 256) gs[j] = g[j];

  float accA[TV], accB[TV];
#pragma unroll
  for (int vv = 0; vv < TV; ++vv) { accA[vv] = 0.f; accB[vv] = 0.f; }

  for (int kc = 0; kc < 8; ++kc) {
    __syncthreads();
    if (t < 128) {
      const int vv = t >> 4;
      const int kk = (t & 15) << 2;
      const float4 s4 = *reinterpret_cast<const float4*>(
          &emb[(size_t)(v0 + vv) * EMB + kc * 64 + kk]);
      xs[vv][kk] = s4.x; xs[vv][kk + 1] = s4.y;
      xs[vv][kk + 2] = s4.z; xs[vv][kk + 3] = s4.w;
    }
    __syncthreads();
    float cA[TV], cB[TV];
#pragma unroll
    for (int vv = 0; vv < TV; ++vv) { cA[vv] = 0.f; cB[vv] = 0.f; }
    for (int q = 0; q < 16; ++q) {
      const int k = kc * 64 + q * 4;
      float2 w[4];
#pragma unroll
      for (int u = 0; u < 4; ++u)
        w[u] = *reinterpret_cast<const float2*>(&W1[(size_t)(k + u) * EMB + j2]);
      float4 xv[TV];
#pragma unroll
      for (int vv = 0; vv < TV; ++vv)
        xv[vv] = *reinterpret_cast<const float4*>(&xs[vv][q * 4]);
#pragma unroll
      for (int u = 0; u < 4; ++u) {
#pragma unroll
        for (int vv = 0; vv < TV; ++vv) {
          const float x = (u == 0) ? xv[vv].x : (u == 1) ? xv[vv].y
                         : (u == 2) ? xv[vv].z : xv[vv].w;
          cA[vv] = fmaf(x, w[u].x, cA[vv]);
          cB[vv] = fmaf(x, w[u].y, cB[vv]);
        }
      }
    }
#pragma unroll
    for (int vv = 0; vv < TV; ++vv) { accA[vv] += cA[vv]; accB[vv] += cB[vv]; }
  }

  float gA = 0.f, gB = 0.f;
  for (int kc = 0; kc < 8; ++kc) {
    float cgA = 0.f, cgB = 0.f;
    for (int q = 0; q < 16; ++q) {
      const int k = kc * 64 + q * 4;
      const float4 gv = *reinterpret_cast<const float4*>(&gs[k]);
      float2 w[4];
#pragma unroll
      for (int u = 0; u < 4; ++u)
        w[u] = *reinterpret_cast<const float2*>(
            &W1[(size_t)(EMB + k + u) * EMB + j2]);
      cgA = fmaf(gv.x, w[0].x, cgA); cgB = fmaf(gv.x, w[0].y, cgB);
      cgA = fmaf(gv.y, w[1].x, cgA); cgB = fmaf(gv.y, w[1].y, cgB);
      cgA = fmaf(gv.z, w[2].x, cgA); cgB = fmaf(gv.z, w[2].y, cgB);
      cgA = fmaf(gv.w, w[3].x, cgA); cgB = fmaf(gv.w, w[3].y, cgB);
    }
    gA += cgA; gB += cgB;
  }

  {
    const float bA = b1[j2], bB = b1[j2 + 1];
#pragma unroll
    for (int vv = 0; vv < TV; ++vv) {
      float hA = (accA[vv] + gA) + bA;
      float hB = (accB[vv] + gB) + bB;
      hA = (hA >= 0.f) ? hA : 0.01f * hA;
      hB = (hB >= 0.f) ? hB : 0.01f * hB;
      *reinterpret_cast<float2*>(&h1s[vv][j2]) = float2{hA, hB};
    }
  }
  __syncthreads();

  if (t < 200) {
    float a2A[TV], a2B[TV];
#pragma unroll
    for (int vv = 0; vv < TV; ++vv) { a2A[vv] = 0.f; a2B[vv] = 0.f; }
    for (int kc = 0; kc < 8; ++kc) {
      float cA[TV], cB[TV];
#pragma unroll
      for (int vv = 0; vv < TV; ++vv) { cA[vv] = 0.f; cB[vv] = 0.f; }
      for (int q = 0; q < 16; ++q) {
        const int k = kc * 64 + q * 4;
        float2 w[4];
#pragma unroll
        for (int u = 0; u < 4; ++u)
          w[u] = *reinterpret_cast<const float2*>(&W2[(size_t)(k + u) * 400 + j2]);
        float4 hv[TV];
#pragma unroll
        for (int vv = 0; vv < TV; ++vv)
          hv[vv] = *reinterpret_cast<const float4*>(&h1s[vv][k]);
#pragma unroll
        for (int u = 0; u < 4; ++u) {
#pragma unroll
          for (int vv = 0; vv < TV; ++vv) {
            const float x = (u == 0) ? hv[vv].x : (u == 1) ? hv[vv].y
                           : (u == 2) ? hv[vv].z : hv[vv].w;
            cA[vv] = fmaf(x, w[u].x, cA[vv]);
            cB[vv] = fmaf(x, w[u].y, cB[vv]);
          }
        }
      }
#pragma unroll
      for (int vv = 0; vv < TV; ++vv) { a2A[vv] += cA[vv]; a2B[vv] += cB[vv]; }
    }
    const float bA = b2[j2], bB = b2[j2 + 1];
#pragma unroll
    for (int vv = 0; vv < TV; ++vv) {
      float hA = a2A[vv] + bA;
      float hB = a2B[vv] + bB;
      hA = (hA >= 0.f) ? hA : 0.01f * hA;
      hB = (hB >= 0.f) ? hB : 0.01f * hB;
      *reinterpret_cast<float2*>(&h2s[vv][j2]) = float2{hA, hB};
    }
  }
  __syncthreads();

  float a3[TV], a3x[TV];
#pragma unroll
  for (int vv = 0; vv < TV; ++vv) { a3[vv] = 0.f; a3x[vv] = 0.f; }
  for (int kc = 0; kc < 8; ++kc) {
    float c3[TV], c3x[TV];
#pragma unroll
    for (int vv = 0; vv < TV; ++vv) { c3[vv] = 0.f; c3x[vv] = 0.f; }
    for (int kk = 0; kk < 50; ++kk) {
      const int k = kc * 50 + kk;
      const float w0 = W3[(size_t)k * CLS + t];
      const float wx = (t == 0) ? W3[(size_t)k * CLS + 256] : 0.f;
#pragma unroll
      for (int vv = 0; vv < TV; ++vv) {
        const float hv = h2s[vv][k];
        c3[vv]  = fmaf(hv, w0, c3[vv]);
        c3x[vv] = fmaf(hv, wx, c3x[vv]);
      }
    }
#pragma unroll
    for (int vv = 0; vv < TV; ++vv) { a3[vv] += c3[vv]; a3x[vv] += c3x[vv]; }
  }

  const float bj = b3[t];
  float li_[TV];
#pragma unroll
  for (int vv = 0; vv < TV; ++vv) li_[vv] = a3[vv] + bj;

#pragma unroll
  for (int vv = 0; vv < TV; ++vv) {
    float m = li_[vv];
#pragma unroll
    for (int off = 1; off < 64; off <<= 1) m = fmaxf(m, __shfl_xor(m, off));
    if ((t & 63) == 0) redw[vv][t >> 6] = m;
  }
  if (t == 0) {
    const float bx = b3[256];
#pragma unroll
    for (int vv = 0; vv < TV; ++vv) li256s[vv] = a3x[vv] + bx;
  }
  __syncthreads();
  if (t < TV) {
    const float m = fmaxf(fmaxf(redw[t][0], redw[t][1]),
                          fmaxf(redw[t][2], redw[t][3]));
    mrs[t] = fmaxf(m, li256s[t]);
  }
  __syncthreads();

#pragma unroll
  for (int vv = 0; vv < TV; ++vv) {
    const int v = v0 + vv;
    const float li = li_[vv];
    const KP sk = tfc(KEYS.hi[v], KEYS.lo[v], 0u, 1u);
    const KP o  = tfc(sk.a, sk.b, 0u, (uint32_t)t);
    const uint32_t bb = o.a ^ o.b;
    const float f = __uint_as_float(0x3f800000u | (bb >> 9)) - 1.0f;
    const float u = fmaxf(1.17549435e-38f, f);
    const float gg = -logf(-logf(u));
    pl[(size_t)v * RSTRIDE + t] = li + gg;
    er[(size_t)v * RSTRIDE + t] = expf(li - mrs[vv]);
  }
  if (t == 0) {
    const float bx = b3[256];
#pragma unroll
    for (int vv = 0; vv < TV; ++vv) {
      const int v = v0 + vv;
      const float li = a3x[vv] + bx;
      const KP sk = tfc(KEYS.hi[v], KEYS.lo[v], 0u, 1u);
      const KP o  = tfc(sk.a, sk.b, 0u, 256u);
      const uint32_t bb = o.a ^ o.b;
      const float f = __uint_as_float(0x3f800000u | (bb >> 9)) - 1.0f;
      const float u = fmaxf(1.17549435e-38f, f);
      const float gg = -logf(-logf(u));
      pl[(size_t)v * RSTRIDE + 256] = li + gg;
      er[(size_t)v * RSTRIDE + 256] = expf(li - mrs[vv]);
    }
  }
}

// ---------------------------------------------------------------------------
// helpers
// ---------------------------------------------------------------------------
#define DPPF(CTRL, OLDI, X) \
  __builtin_amdgcn_update_dpp((int)(OLDI), (X), (CTRL), 0xF, 0xF, false)
#define SRED(CTRL) { S += __int_as_float(DPPF(CTRL, 0, __float_as_int(S))); }

__device__ __forceinline__ uint32_t ordmap(float f) {
  const uint32_t s = __float_as_uint(f);
  return s ^ (0x80000000u | (uint32_t)((int32_t)s >> 31));
}

#define WG_SCOPE __HIP_MEMORY_SCOPE_WORKGROUP

// ---------------------------------------------------------------------------
// K2b: per-row descending sort of 257 perturbed logits by (ordmap(pl), ~idx).
// First 320 u16 of each pl row overwritten IN PLACE with sorted class ids.
// ---------------------------------------------------------------------------
__global__ __launch_bounds__(256) void sortrows(float* __restrict__ plbuf) {
  __shared__ uint64_t keys[4][512];
  const int t = threadIdx.x;
  const int w = t >> 6;
  const int lane = t & 63;
  const int v = blockIdx.x * 4 + w;
  const float* row = plbuf + (size_t)v * RSTRIDE;

#pragma unroll
  for (int j = 0; j < 8; ++j) {
    const int i = lane + 64 * j;
    uint32_t om = 0u;
    if (i < CLS) om = ordmap(row[i]);
    keys[w][i] = ((uint64_t)om << 9) | (uint64_t)(511 - i);
  }
  __syncthreads();

  for (int k = 2; k <= 512; k <<= 1) {
    for (int j = k >> 1; j > 0; j >>= 1) {
#pragma unroll
      for (int m = 0; m < 4; ++m) {
        const int p  = lane + 64 * m;
        const int i  = ((p & ~(j - 1)) << 1) | (p & (j - 1));
        const int ix = i | j;
        const uint64_t a = keys[w][i], b = keys[w][ix];
        const bool sw = ((i & k) == 0) ? (a < b) : (a > b);
        if (sw) { keys[w][i] = b; keys[w][ix] = a; }
      }
      __syncthreads();
    }
  }

  uint16_t* o16 = reinterpret_cast<uint16_t*>(plbuf) + (size_t)v * (RSTRIDE * 2);
#pragma unroll
  for (int j = 0; j < 5; ++j) {
    const int i = lane + 64 * j;
    if (i < 320) o16[i] = (uint16_t)(511u - (uint32_t)(keys[w][i] & 511u));
  }
}

// ---------------------------------------------------------------------------
// K3: scan10 — two-wave relay. Wave A (wid 0) owns odd rows, wave B (wid 1)
// even rows, wave 2 = producer. Loop-carried state crosses waves as ONE LDS
// word: relay = (v<<19)|(n_used<<9)|chosen. Per-row prep (gather/or/readback,
// private bbuf slots) runs off the relay path. Mask semantics = scan9's
// (gather sees colors<=v-2, single hf fix vs relayed chosen).
// ---------------------------------------------------------------------------
__global__ __launch_bounds__(192) void scan10(
    const int* __restrict__ nbrG, const uint32_t* __restrict__ scG,
    unsigned* __restrict__ rawnu, float* __restrict__ out)
{
  __shared__ int colors[NV];            // 32 KB
  __shared__ uint32_t scR[32][160];     // 20 KB ring
  __shared__ int nbrRing[1024];         // 4 KB
  __shared__ unsigned bbufW[2][2][16];  // per-consumer private slots
  __shared__ int prod_done, consA_done, consB_done;
  __shared__ unsigned relay;            // (v<<19)|(nu<<9)|cp

  const int t = threadIdx.x;
  const int wid = t >> 6;               // 0=consA(odd) 1=consB(even) 2=producer
  const int lane = t & 63;
  const int ln32 = lane & 31;
  const uint16_t* scR16 = reinterpret_cast<const uint16_t*>(&scR[0][0]);

  for (int i = t; i < NV; i += 192) colors[i] = -1;
  if (t == 0) {
    colors[0] = 0; prod_done = 0; consA_done = 0; consB_done = 0;
    relay = (0u << 19) | (1u << 9) | 0u;   // post-row-0 state: nu=1, cp=0
  }
  __syncthreads();

  if (wid == 2) {
    // ================= producer wave =================
    for (int pc = 0; pc < 1024; ++pc) {
      for (;;) {
        const int ca = __hip_atomic_load(&consA_done, __ATOMIC_ACQUIRE, WG_SCOPE);
        const int cb = __hip_atomic_load(&consB_done, __ATOMIC_ACQUIRE, WG_SCOPE);
        if ((ca < cb ? ca : cb) >= pc - 3) break;
        __builtin_amdgcn_s_sleep(1);
      }
      uint32_t x[8], y[8], z[8];
#pragma unroll
      for (int r = 0; r < 8; ++r) {
        const size_t base = (size_t)(pc * 8 + r) * RSTRIDE;   // u32 units
        x[r] = scG[base + lane];
        y[r] = scG[base + 64 + lane];
        z[r] = (lane < 32) ? scG[base + 128 + lane] : 0u;
      }
      const int4 nb4 = *reinterpret_cast<const int4*>(nbrG + pc * 256 + 4 * lane);
#pragma unroll
      for (int r = 0; r < 8; ++r) {
        const int slot = (pc * 8 + r) & 31;
        scR[slot][lane] = x[r];
        scR[slot][64 + lane] = y[r];
        if (lane < 32) scR[slot][128 + lane] = z[r];
      }
      *reinterpret_cast<int4*>(&nbrRing[((pc & 3) << 8) + 4 * lane]) = nb4;
      if (lane == 0)
        __hip_atomic_store(&prod_done, pc + 1, __ATOMIC_RELEASE, WG_SCOPE);
    }
    return;
  }

  // ================= consumer waves =================
  const int v0 = 1 + wid;               // A:1  B:2
  unsigned* const slot0 = bbufW[wid][0];
  unsigned* const slot1 = bbufW[wid][1];

  int pdc = 0;
  while (pdc < 1)
    pdc = __hip_atomic_load(&prod_done, __ATOMIC_ACQUIRE, WG_SCOPE);

  int c0 = 0, c1 = 0;
  bool fb0 = false, fb1 = false, hf = false;

#define PREP10(V) {                                                            \
    const int v_ = (V);                                                        \
    while (pdc <= (v_ >> 3))                                                   \
      pdc = __hip_atomic_load(&prod_done, __ATOMIC_ACQUIRE, WG_SCOPE);         \
    const uint32_t cw_ = scR[v_ & 31][lane];                                   \
    const int nb_ = nbrRing[(((v_ >> 3) & 3) << 8) + ((v_ & 7) << 5) + ln32];  \
    unsigned* const sl_ = ((v_ >> 1) & 1) ? slot1 : slot0;                     \
    sl_[lane & 15] = 0u;                                                       \
    const int cg_ = colors[nb_];                                               \
    hf = (__ballot(nb_ == v_ - 1) != 0ULL);                                    \
    if (cg_ >= 0) atomicOr(&sl_[cg_ >> 5], 1u << (cg_ & 31));                  \
    c0 = (int)(cw_ & 0xFFFFu); c1 = (int)(cw_ >> 16);                          \
    const unsigned w0_ = sl_[c0 >> 5];                                         \
    const unsigned w1_ = sl_[c1 >> 5];                                         \
    fb0 = !((w0_ >> (c0 & 31)) & 1u);                                          \
    fb1 = !((w1_ >> (c1 & 31)) & 1u);                                          \
  }

  PREP10(v0)

  for (int v = v0; v < NV; v += 2) {
    // ---- poll relay for seq v-1 ----
    unsigned r;
    do {
      r = __hip_atomic_load(&relay, __ATOMIC_ACQUIRE, WG_SCOPE);
    } while ((r >> 19) != (unsigned)(v - 1));
    const int nu = (int)((r >> 9) & 0x3FFu);
    const int cp = (int)(r & 0x1FFu);

    // ---- critical ----
    int raw = 256;
    {
      const bool ok0 = fb0 && (c0 < nu || c0 == 256) && !(hf && c0 == cp);
      const bool ok1 = fb1 && (c1 < nu || c1 == 256) && !(hf && c1 == cp);
      uint64_t b_ = __ballot(ok0 || ok1);
      if (b_) {
        const int sel = ok0 ? c0 : c1;
        raw = __builtin_amdgcn_readlane(sel, (int)__builtin_ctzll(b_));
      } else {
        // slow path: ranks 128..319 of row v against own full slot mask
        const int sBv = (v & 31) * 320;
        unsigned* const sl_ = ((v >> 1) & 1) ? slot1 : slot0;
        const int x2 = scR16[sBv + 128 + lane];
        const int x3 = scR16[sBv + 192 + lane];
        const int x4 = scR16[sBv + 256 + lane];
        const unsigned q2 = sl_[x2 >> 5];
        const unsigned q3 = sl_[x3 >> 5];
        const unsigned q4 = sl_[x4 >> 5];
        const bool o2 = (!((q2 >> (x2 & 31)) & 1u)) &&
                        (x2 < nu || x2 == 256) && !(hf && x2 == cp);
        const bool o3 = (!((q3 >> (x3 & 31)) & 1u)) &&
                        (x3 < nu || x3 == 256) && !(hf && x3 == cp);
        const bool o4 = (!((q4 >> (x4 & 31)) & 1u)) &&
                        (x4 < nu || x4 == 256) && !(hf && x4 == cp);
        if ((b_ = __ballot(o2)))
          raw = __builtin_amdgcn_readlane(x2, (int)__builtin_ctzll(b_));
        else if ((b_ = __ballot(o3)))
          raw = __builtin_amdgcn_readlane(x3, (int)__builtin_ctzll(b_));
        else if ((b_ = __ballot(o4)))
          raw = __builtin_amdgcn_readlane(x4, (int)__builtin_ctzll(b_));
      }
    }
    const bool isnew = (raw == 256);
    const int chosen = isnew ? nu : raw;
    const unsigned nuN = (unsigned)nu + (isnew ? 1u : 0u);
    if (lane == 0) {
      colors[v] = chosen;                      // before relay (release order)
      rawnu[v] = (unsigned)raw | ((unsigned)nu << 16);
      __hip_atomic_store(&relay,
          ((unsigned)v << 19) | (nuN << 9) | (unsigned)chosen,
          __ATOMIC_RELEASE, WG_SCOPE);
    }

    // ---- chunk-consumed update (A at v%8==7, B at v%8==6) ----
    if ((v & 7) == 7 - wid) {
      const int dn = (v + 1 + wid) >> 3;
      if (lane == 0) {
        if (wid == 0)
          __hip_atomic_store(&consA_done, dn, __ATOMIC_RELEASE, WG_SCOPE);
        else
          __hip_atomic_store(&consB_done, dn, __ATOMIC_RELEASE, WG_SCOPE);
      }
    }

    // ---- prep next own row (off relay path) ----
    if (v + 2 < NV) PREP10(v + 2)
  }

  if (lane == 0) {
    if (wid == 0)
      __hip_atomic_store(&consA_done, 1024, __ATOMIC_RELEASE, WG_SCOPE);
    else
      __hip_atomic_store(&consB_done, 1024, __ATOMIC_RELEASE, WG_SCOPE);
  }

  // Wave A finishes last (row 8191; B's writes visible via relay acquires).
  if (wid == 0)
    for (int i = lane; i < NV; i += 64) out[i] = (float)colors[i];
}

// ---------------------------------------------------------------------------
// K4: parallel logp recomputation (unchanged).
// ---------------------------------------------------------------------------
__global__ __launch_bounds__(256) void logp_part(
    const float* __restrict__ outF, const int* __restrict__ nbrG,
    const float* __restrict__ er, const unsigned* __restrict__ rawnu,
    double* __restrict__ partd)
{
  __shared__ unsigned bb[4][16];
  const int t = threadIdx.x;
  const int w = t >> 6;
  const int lane = t & 63;
  const int ln32 = lane & 31;
  const int b = blockIdx.x;

  double a = 0.0;
  for (int i = 0; i < 32; ++i) {
    const int v = b * 128 + w * 32 + i;
    if (v == 0) continue;
    const unsigned val = rawnu[v];
    const int raw = (int)(val & 0xFFFFu);
    const int nu  = (int)(val >> 16);

    bb[w][lane & 15] = 0u;
    const int u = nbrG[(size_t)v * DEG + ln32];
    const int cu = (u < v) ? (int)outF[u] : -1;
    if (cu >= 0) atomicOr(&bb[w][cu >> 5], 1u << (cu & 31));
    unsigned bwp[4];
#pragma unroll
    for (int j = 0; j < 4; ++j) bwp[j] = bb[w][(lane >> 5) + 2 * j];
    const unsigned bw8 = bb[w][8];

    const size_t base = (size_t)v * RSTRIDE;
    bool mk[4];
    float e[4];
#pragma unroll
    for (int j = 0; j < 4; ++j) {
      const int c = lane + 64 * j;
      mk[j] = (((bwp[j] >> ln32) & 1u) != 0u) || (c >= nu);
      e[j] = mk[j] ? 0.f : er[base + c];
    }
    const bool mkX = ((bw8 & 1u) != 0u);
    const float eX = er[base + 256];
    const float e4 = (!mkX && lane == 0) ? eX : 0.f;

    float S = ((e[0] + e[1]) + (e[2] + e[3])) + e4;
    SRED(0x111) SRED(0x112) SRED(0x114) SRED(0x118) SRED(0x142) SRED(0x143)
    const float Sall = __int_as_float(
        __builtin_amdgcn_readlane(__float_as_int(S), 63));

    const bool isnew = (raw == 256);
    const int jsel  = isnew ? 4 : (raw >> 6);
    const int owner = isnew ? 0 : (raw & 63);
    const float cand = (jsel == 0) ? e[0] : (jsel == 1) ? e[1]
                     : (jsel == 2) ? e[2] : (jsel == 3) ? e[3] : e4;
    const float praw = __int_as_float(
        __builtin_amdgcn_readlane(__float_as_int(cand), owner));

    const float p = praw / Sall;
    a += (double)(logf(p + 1e-8f) - logf(1e-8f));
  }
  if (lane == 0) partd[b * 4 + w] = a;
}

__global__ __launch_bounds__(64) void finalize(
    const double* __restrict__ partd, const unsigned* __restrict__ rawnu,
    const float* __restrict__ baseline, float* __restrict__ out)
{
  if (threadIdx.x == 0) {
    double lp = 0.0;
    for (int i = 0; i < 256; ++i) lp += partd[i];
    const unsigned val = rawnu[NV - 1];
    const unsigned nf = (val >> 16) + (((val & 0xFFFFu) == 256u) ? 1u : 0u);
    out[NV] = ((float)nf - baseline[0]) * (float)lp / 8192.0f;
  }
}

// ---------------------------------------------------------------------------
extern "C" void kernel_launch(void* const* d_in, const int* in_sizes, int n_in,
                              void* d_out, int out_size, void* d_ws, size_t ws_size,
                              hipStream_t stream) {
  const float* emb      = (const float*)d_in[0];
  const int*   nbr      = (const int*)d_in[1];
  const float* W1       = (const float*)d_in[2];
  const float* b1       = (const float*)d_in[3];
  const float* W2       = (const float*)d_in[4];
  const float* b2       = (const float*)d_in[5];
  const float* W3       = (const float*)d_in[6];
  const float* b3       = (const float*)d_in[7];
  const float* baseline = (const float*)d_in[8];
  float* out = (float*)d_out;

  char* ws = (char*)d_ws;
  float* g     = (float*)ws;                               // 2 KB
  float* plbuf = (float*)(ws + 2048);                      // 8192*260*4 B
  float* erbuf = (float*)(ws + 2048 + NV * RSTRIDE * 4);   // 8192*260*4 B
  float* part  = erbuf;  // alias: consumed by colmean_fin BEFORE mlp3i writes er
  unsigned* rawnu = (unsigned*)(ws + 2048);                // aliases dead pl rows
  double*   partd = (double*)(ws + 2048 + 65536);          // 2 KB

  colmean_part<<<64, 256, 0, stream>>>(emb, part);
  colmean_fin<<<1, 256, 0, stream>>>(part, g);
  mlp3i<<<NV / TV, 256, 0, stream>>>(emb, g, W1, b1, W2, b2, W3, b3, plbuf, erbuf);
  sortrows<<<NV / 4, 256, 0, stream>>>(plbuf);
  scan10<<<1, 192, 0, stream>>>(nbr, (const uint32_t*)plbuf, rawnu, out);
  logp_part<<<64, 256, 0, stream>>>((const float*)out, nbr, erbuf, rawnu, partd);
  finalize<<<1, 64, 0, stream>>>(partd, rawnu, baseline, out);
}